// Round 3
// baseline (1293.752 us; speedup 1.0000x reference)
//
#include <hip/hip_runtime.h>

typedef __attribute__((ext_vector_type(8))) _Float16 half8;
typedef __attribute__((ext_vector_type(4))) _Float16 half4;
typedef __attribute__((ext_vector_type(4))) float f32x4;

// ---------------- encode: x0 = fp16(node_emb + type_emb[type]) ----------------
__global__ void k_encode(const float* __restrict__ emb, const float* __restrict__ temb,
                         const int* __restrict__ tids, _Float16* __restrict__ x, int n) {
  int i = blockIdx.x * 256 + threadIdx.x;  // one thread per 8 columns
  if (i >= n * 64) return;
  int node = i >> 6, c = (i & 63) << 3;
  const float* e = emb + (size_t)node * 512 + c;
  const float* t = temb + (size_t)tids[node] * 512 + c;
  float4 a0 = *(const float4*)e, a1 = *(const float4*)(e + 4);
  float4 b0 = *(const float4*)t, b1 = *(const float4*)(t + 4);
  half8 o;
  o[0] = (_Float16)(a0.x + b0.x); o[1] = (_Float16)(a0.y + b0.y);
  o[2] = (_Float16)(a0.z + b0.z); o[3] = (_Float16)(a0.w + b0.w);
  o[4] = (_Float16)(a1.x + b1.x); o[5] = (_Float16)(a1.y + b1.y);
  o[6] = (_Float16)(a1.z + b1.z); o[7] = (_Float16)(a1.w + b1.w);
  *(half8*)(x + (size_t)node * 512 + c) = o;
}

// ---------------- CSR build ----------------
__global__ void k_zero(int* __restrict__ p, int n) {
  int i = blockIdx.x * 256 + threadIdx.x;
  if (i < n) p[i] = 0;
}

__global__ void k_hist(const int* __restrict__ d0, const int* __restrict__ d1,
                       const int* __restrict__ d2, int* __restrict__ counts, int E, int Np1) {
  int e = blockIdx.x * 256 + threadIdx.x;
  if (e >= E) return;
  int r = blockIdx.y;
  const int* d = (r == 0) ? d0 : ((r == 1) ? d1 : d2);
  atomicAdd(&counts[r * Np1 + d[e] + 1], 1);
}

// one block (1024 thr) per relation; inclusive scan of counts -> row_ptr
__global__ void k_scan(const int* __restrict__ counts, int* __restrict__ rowp, int n) {
  __shared__ int wsum[16];
  int r = blockIdx.x;
  const int* c = counts + (size_t)r * n;
  int* o = rowp + (size_t)r * n;
  int lane = threadIdx.x & 63, w = threadIdx.x >> 6;
  int off = 0;
  for (int base = 0; base < n; base += 1024) {
    int i = base + threadIdx.x;
    int v = (i < n) ? c[i] : 0;
    int sc = v;
    #pragma unroll
    for (int d = 1; d < 64; d <<= 1) {
      int t = __shfl_up(sc, (unsigned)d);
      if (lane >= d) sc += t;
    }
    if (lane == 63) wsum[w] = sc;
    __syncthreads();
    int wo = 0, tot = 0;
    #pragma unroll
    for (int ww = 0; ww < 16; ++ww) {
      int s = wsum[ww];
      if (ww < w) wo += s;
      tot += s;
    }
    if (i < n) o[i] = sc + wo + off;
    off += tot;
    __syncthreads();
  }
}

__global__ void k_copy(const int* __restrict__ a, int* __restrict__ b, int n) {
  int i = blockIdx.x * 256 + threadIdx.x;
  if (i < n) b[i] = a[i];
}

__global__ void k_fill(const int* __restrict__ s0, const int* __restrict__ s1, const int* __restrict__ s2,
                       const int* __restrict__ d0, const int* __restrict__ d1, const int* __restrict__ d2,
                       int* __restrict__ cursor, int* __restrict__ col_src, int E, int Np1) {
  int e = blockIdx.x * 256 + threadIdx.x;
  if (e >= E) return;
  int r = blockIdx.y;
  const int* dp = (r == 0) ? d0 : ((r == 1) ? d1 : d2);
  const int* sp = (r == 0) ? s0 : ((r == 1) ? s1 : s2);
  int pos = atomicAdd(&cursor[r * Np1 + dp[e]], 1);
  if (pos >= 0 && pos < E) col_src[(size_t)r * E + pos] = sp[e];
}

// ---------------- aggregate: one wave per (node, relation); fp16 in/out, fp32 accum ----------------
__global__ void k_aggregate(const _Float16* __restrict__ x, _Float16* __restrict__ agg,
                            const int* __restrict__ rowp, const int* __restrict__ col_src,
                            int N, int E) {
  int wid = (blockIdx.x * 256 + threadIdx.x) >> 6;
  int lane = threadIdx.x & 63;
  if (wid >= 3 * N) return;
  int r = wid / N;
  int n = wid - r * N;
  int beg = rowp[r * (N + 1) + n], end = rowp[r * (N + 1) + n + 1];
  const int* cs = col_src + (size_t)r * E;
  float acc[8] = {0, 0, 0, 0, 0, 0, 0, 0};
  for (int e = beg; e < end; ++e) {
    int s = cs[e];
    half8 v = *(const half8*)(x + (size_t)s * 512 + lane * 8);
    #pragma unroll
    for (int j = 0; j < 8; ++j) acc[j] += (float)v[j];
  }
  half8 o;
  #pragma unroll
  for (int j = 0; j < 8; ++j) o[j] = (_Float16)acc[j];
  *(half8*)(agg + (size_t)n * 1536 + r * 512 + lane * 8) = o;
}

// ---------------- weight transpose+cast: Bt[n][k] fp16 from Bl[k<512][n], Br[k-512][n] ----------------
__global__ void k_transpose(const float* __restrict__ Bl, const float* __restrict__ Br,
                            _Float16* __restrict__ Bt, int No, int K) {
  __shared__ float tile[64][65];
  int k0 = blockIdx.x * 64, n0 = blockIdx.y * 64;
  int nl = threadIdx.x & 63, kb = threadIdx.x >> 6;
  #pragma unroll
  for (int i = 0; i < 16; ++i) {
    int kl = kb + i * 4;
    int krow = k0 + kl;
    float v = (krow < 512) ? Bl[(size_t)krow * No + n0 + nl]
                           : Br[(size_t)(krow - 512) * No + n0 + nl];
    tile[kl][nl] = v;
  }
  __syncthreads();
  int kl = threadIdx.x & 63, nb = threadIdx.x >> 6;
  #pragma unroll
  for (int i = 0; i < 16; ++i) {
    int n2 = nb + i * 4;
    Bt[(size_t)(n0 + n2) * K + k0 + kl] = (_Float16)tile[kl][n2];
  }
}

// ---------------- RGCN GEMM: C[M,Ncols] = [Ain | Aagg] @ Bt^T, fp16 out, optional relu ----------------
#define LSTR 40

__global__ __launch_bounds__(256) void k_gemm_rgcn(
    const _Float16* __restrict__ Ain, const _Float16* __restrict__ Aagg,
    const _Float16* __restrict__ Bt, _Float16* __restrict__ C,
    int M, int Ncols, int K, int relu) {
  __shared__ __align__(16) _Float16 As[128 * LSTR];
  __shared__ __align__(16) _Float16 Bs[128 * LSTR];
  int tid = threadIdx.x;
  int bm0 = blockIdx.x * 128, bn0 = blockIdx.y * 128;
  int lane = tid & 63, wv = tid >> 6;
  int wm = wv & 1, wn = wv >> 1;
  int l16 = lane & 15, quad = lane >> 4;
  int srow = tid >> 1, scs = (tid & 1) * 16;
  int agr = bm0 + srow; if (agr >= M) agr = M - 1;
  int bgn = bn0 + srow;

  f32x4 acc[4][4];
  #pragma unroll
  for (int i = 0; i < 4; ++i)
    #pragma unroll
    for (int j = 0; j < 4; ++j) acc[i][j] = (f32x4){0.f, 0.f, 0.f, 0.f};

  for (int k0 = 0; k0 < K; k0 += 32) {
    __syncthreads();
    {
      const _Float16* src = (k0 < 512)
          ? Ain + (size_t)agr * 512 + k0 + scs
          : Aagg + (size_t)agr * 1536 + (k0 - 512) + scs;
      *(uint4*)&As[srow * LSTR + scs] = *(const uint4*)src;
      *(uint4*)&As[srow * LSTR + scs + 8] = *(const uint4*)(src + 8);
    }
    {
      const _Float16* src = Bt + (size_t)bgn * K + k0 + scs;
      *(uint4*)&Bs[srow * LSTR + scs] = *(const uint4*)src;
      *(uint4*)&Bs[srow * LSTR + scs + 8] = *(const uint4*)(src + 8);
    }
    __syncthreads();
    half8 af[4], bf[4];
    #pragma unroll
    for (int i = 0; i < 4; ++i)
      af[i] = *(const half8*)&As[(wm * 64 + i * 16 + l16) * LSTR + quad * 8];
    #pragma unroll
    for (int j = 0; j < 4; ++j)
      bf[j] = *(const half8*)&Bs[(wn * 64 + j * 16 + l16) * LSTR + quad * 8];
    #pragma unroll
    for (int i = 0; i < 4; ++i)
      #pragma unroll
      for (int j = 0; j < 4; ++j)
        acc[i][j] = __builtin_amdgcn_mfma_f32_16x16x32_f16(af[i], bf[j], acc[i][j], 0, 0, 0);
  }

  #pragma unroll
  for (int i = 0; i < 4; ++i)
    #pragma unroll
    for (int j = 0; j < 4; ++j)
      #pragma unroll
      for (int rg = 0; rg < 4; ++rg) {
        int row = bm0 + wm * 64 + i * 16 + quad * 4 + rg;
        int col = bn0 + wn * 64 + j * 16 + l16;
        if (row < M) {
          float v = acc[i][j][rg];
          if (relu) v = fmaxf(v, 0.f);
          C[(size_t)row * Ncols + col] = (_Float16)v;
        }
      }
}

// ---------------- Link GEMM: h1 = fp16(BN(relu(feats @ W1 + b1))), feats gathered from z (fp16) ----------------
__global__ __launch_bounds__(256) void k_gemm_link(
    const _Float16* __restrict__ z, const int* __restrict__ pairs,
    const _Float16* __restrict__ Bt,
    const float* __restrict__ b1, const float* __restrict__ bng, const float* __restrict__ bnb,
    const float* __restrict__ bnm, const float* __restrict__ bnv,
    _Float16* __restrict__ h1, int P, int K) {
  __shared__ __align__(16) _Float16 As[128 * LSTR];
  __shared__ __align__(16) _Float16 Bs[128 * LSTR];
  int tid = threadIdx.x;
  int bm0 = blockIdx.x * 128, bn0 = blockIdx.y * 128;
  int lane = tid & 63, wv = tid >> 6;
  int wm = wv & 1, wn = wv >> 1;
  int l16 = lane & 15, quad = lane >> 4;
  int srow = tid >> 1, scs = (tid & 1) * 16;
  int p = bm0 + srow; if (p >= P) p = P - 1;
  int sp = pairs[p], dp = pairs[P + p];
  const _Float16* zs = z + (size_t)sp * 256;
  const _Float16* zd = z + (size_t)dp * 256;
  int bgn = bn0 + srow;

  f32x4 acc[4][4];
  #pragma unroll
  for (int i = 0; i < 4; ++i)
    #pragma unroll
    for (int j = 0; j < 4; ++j) acc[i][j] = (f32x4){0.f, 0.f, 0.f, 0.f};

  for (int k0 = 0; k0 < K; k0 += 32) {
    __syncthreads();
    int seg = k0 >> 8;
    int kk = (k0 & 255) + scs;
    __attribute__((aligned(16))) _Float16 tmp[16];
    if (seg == 0) {
      *(uint4*)tmp = *(const uint4*)(zs + kk);
      *(uint4*)(tmp + 8) = *(const uint4*)(zs + kk + 8);
    } else if (seg == 1) {
      *(uint4*)tmp = *(const uint4*)(zd + kk);
      *(uint4*)(tmp + 8) = *(const uint4*)(zd + kk + 8);
    } else {
      half8 u0 = *(const half8*)(zs + kk), u1 = *(const half8*)(zs + kk + 8);
      half8 v0 = *(const half8*)(zd + kk), v1 = *(const half8*)(zd + kk + 8);
      #pragma unroll
      for (int j = 0; j < 8; ++j) {
        tmp[j] = (_Float16)((float)u0[j] * (float)v0[j]);
        tmp[j + 8] = (_Float16)((float)u1[j] * (float)v1[j]);
      }
    }
    *(uint4*)&As[srow * LSTR + scs] = *(const uint4*)tmp;
    *(uint4*)&As[srow * LSTR + scs + 8] = *(const uint4*)(tmp + 8);
    {
      const _Float16* src = Bt + (size_t)bgn * K + k0 + scs;
      *(uint4*)&Bs[srow * LSTR + scs] = *(const uint4*)src;
      *(uint4*)&Bs[srow * LSTR + scs + 8] = *(const uint4*)(src + 8);
    }
    __syncthreads();
    half8 af[4], bf[4];
    #pragma unroll
    for (int i = 0; i < 4; ++i)
      af[i] = *(const half8*)&As[(wm * 64 + i * 16 + l16) * LSTR + quad * 8];
    #pragma unroll
    for (int j = 0; j < 4; ++j)
      bf[j] = *(const half8*)&Bs[(wn * 64 + j * 16 + l16) * LSTR + quad * 8];
    #pragma unroll
    for (int i = 0; i < 4; ++i)
      #pragma unroll
      for (int j = 0; j < 4; ++j)
        acc[i][j] = __builtin_amdgcn_mfma_f32_16x16x32_f16(af[i], bf[j], acc[i][j], 0, 0, 0);
  }

  #pragma unroll
  for (int i = 0; i < 4; ++i)
    #pragma unroll
    for (int j = 0; j < 4; ++j) {
      int col = bn0 + wn * 64 + j * 16 + l16;
      float bb1 = b1[col], m = bnm[col], rs = rsqrtf(bnv[col] + 1e-5f);
      float gg = bng[col], bb = bnb[col];
      #pragma unroll
      for (int rg = 0; rg < 4; ++rg) {
        int row = bm0 + wm * 64 + i * 16 + quad * 4 + rg;
        if (row < P) {
          float v = fmaxf(acc[i][j][rg] + bb1, 0.f);
          v = (v - m) * rs * gg + bb;
          h1[(size_t)row * 256 + col] = (_Float16)v;
        }
      }
    }
}

// ---------------- LN + relu + residual: x2 = x1 + relu(LN(h)); fp16 in/out ----------------
__global__ void k_ln_res(const _Float16* __restrict__ h, const _Float16* __restrict__ x1,
                         const float* __restrict__ g, const float* __restrict__ b,
                         _Float16* __restrict__ out, int N) {
  int wid = (blockIdx.x * 256 + threadIdx.x) >> 6;
  int lane = threadIdx.x & 63;
  if (wid >= N) return;
  int c = lane * 8;
  half8 hv = *(const half8*)(h + (size_t)wid * 512 + c);
  float hf[8];
  float s = 0.f, sq = 0.f;
  #pragma unroll
  for (int j = 0; j < 8; ++j) {
    hf[j] = (float)hv[j];
    s += hf[j];
    sq += hf[j] * hf[j];
  }
  #pragma unroll
  for (int off = 32; off; off >>= 1) {
    s += __shfl_down(s, (unsigned)off);
    sq += __shfl_down(sq, (unsigned)off);
  }
  s = __shfl(s, 0); sq = __shfl(sq, 0);
  float mu = s * (1.f / 512.f);
  float var = sq * (1.f / 512.f) - mu * mu;
  float rs = rsqrtf(var + 1e-5f);
  float4 g0 = *(const float4*)(g + c), g1 = *(const float4*)(g + c + 4);
  float4 b0 = *(const float4*)(b + c), b1 = *(const float4*)(b + c + 4);
  float gf[8] = {g0.x, g0.y, g0.z, g0.w, g1.x, g1.y, g1.z, g1.w};
  float bf[8] = {b0.x, b0.y, b0.z, b0.w, b1.x, b1.y, b1.z, b1.w};
  half8 xv = *(const half8*)(x1 + (size_t)wid * 512 + c);
  half8 o;
  #pragma unroll
  for (int j = 0; j < 8; ++j) {
    float xw = (float)xv[j];
    o[j] = (_Float16)(xw + fmaxf((hf[j] - mu) * rs * gf[j] + bf[j], 0.f));
  }
  *(half8*)(out + (size_t)wid * 512 + c) = o;
}

// ---------------- score ----------------
__global__ void k_score(const _Float16* __restrict__ h1, const float* __restrict__ w2,
                        const float* __restrict__ b2, const int* __restrict__ pairs,
                        const int* __restrict__ degrees, const float* __restrict__ alpha,
                        const float* __restrict__ beta, float* __restrict__ out, int P) {
  int wid = (blockIdx.x * 256 + threadIdx.x) >> 6;
  int lane = threadIdx.x & 63;
  if (wid >= P) return;
  int c = lane * 4;
  half4 hv = *(const half4*)(h1 + (size_t)wid * 256 + c);
  float4 wv = *(const float4*)(w2 + c);
  float s = (float)hv[0] * wv.x + (float)hv[1] * wv.y + (float)hv[2] * wv.z + (float)hv[3] * wv.w;
  #pragma unroll
  for (int off = 32; off; off >>= 1) s += __shfl_down(s, (unsigned)off);
  if (lane == 0) {
    int sp = pairs[wid], dp = pairs[P + wid];
    float sd = (float)max(degrees[sp], 1);
    float dd = (float)max(degrees[dp], 1);
    float base = s + b2[0] - fmaxf(alpha[0], 0.f) * logf(sd) - fmaxf(beta[0], 0.f) * logf(dd);
    out[wid] = base / (sqrtf(sd) * sqrtf(dd) + 1e-8f);
  }
}

extern "C" void kernel_launch(void* const* d_in, const int* in_sizes, int n_in,
                              void* d_out, int out_size, void* d_ws, size_t ws_size,
                              hipStream_t stream) {
  const int N = 50000, E = 200000, P = 100000;
  const int Np1 = N + 1;
  const int* node_type = (const int*)d_in[0];
  const int* src0 = (const int*)d_in[1]; const int* dst0 = (const int*)d_in[2];
  const int* src1 = (const int*)d_in[3]; const int* dst1 = (const int*)d_in[4];
  const int* src2 = (const int*)d_in[5]; const int* dst2 = (const int*)d_in[6];
  const int* pairs = (const int*)d_in[7];
  const int* degrees = (const int*)d_in[8];
  const float* node_emb = (const float*)d_in[9];
  const float* type_emb = (const float*)d_in[10];
  const float* w_loop_in = (const float*)d_in[11];
  const float* w_rel_in = (const float*)d_in[12];
  const float* w_loop_res = (const float*)d_in[13];
  const float* w_rel_res = (const float*)d_in[14];
  const float* ln_g = (const float*)d_in[15];
  const float* ln_b = (const float*)d_in[16];
  const float* w_loop_out = (const float*)d_in[17];
  const float* w_rel_out = (const float*)d_in[18];
  const float* lp_w1 = (const float*)d_in[19];
  const float* lp_b1 = (const float*)d_in[20];
  const float* bn_g = (const float*)d_in[21];
  const float* bn_b = (const float*)d_in[22];
  const float* bn_mean = (const float*)d_in[23];
  const float* bn_var = (const float*)d_in[24];
  const float* lp_w2 = (const float*)d_in[25];
  const float* lp_b2 = (const float*)d_in[26];
  const float* alpha = (const float*)d_in[27];
  const float* beta = (const float*)d_in[28];
  float* out = (float*)d_out;

  char* ws = (char*)d_ws;
  size_t off = 0;
  auto alloc = [&](size_t bytes) {
    void* p = ws + off;
    off = (off + bytes + 255) & ~(size_t)255;
    return p;
  };
  _Float16* xb0 = (_Float16*)alloc((size_t)N * 512 * 2);   // 51.2 MB
  _Float16* xb1 = (_Float16*)alloc((size_t)N * 512 * 2);   // 51.2 MB
  _Float16* agg = (_Float16*)alloc((size_t)N * 1536 * 2);  // 153.6 MB
  _Float16* Bt = (_Float16*)alloc((size_t)512 * 2048 * 2); // 2 MB
  int* counts = (int*)alloc((size_t)3 * Np1 * 4);
  int* rowp = (int*)alloc((size_t)3 * Np1 * 4);
  int* cursor = (int*)alloc((size_t)3 * Np1 * 4);
  int* col_src = (int*)alloc((size_t)3 * E * 4);
  if (off > ws_size) return;  // workspace too small -> fail visibly, not crash

  // aliases (lifetimes disjoint)
  _Float16* z = xb1;   // x1 dead after ln_res
  _Float16* h1 = agg;  // agg dead after layer-3 gemm

  // CSR build (dst arrays shared by all 3 layers)
  k_zero<<<(3 * Np1 + 255) / 256, 256, 0, stream>>>(counts, 3 * Np1);
  dim3 gE((E + 255) / 256, 3);
  k_hist<<<gE, 256, 0, stream>>>(dst0, dst1, dst2, counts, E, Np1);
  k_scan<<<3, 1024, 0, stream>>>(counts, rowp, Np1);
  k_copy<<<(3 * Np1 + 255) / 256, 256, 0, stream>>>(rowp, cursor, 3 * Np1);
  k_fill<<<gE, 256, 0, stream>>>(src0, src1, src2, dst0, dst1, dst2, cursor, col_src, E, Np1);

  // encode
  k_encode<<<(N * 64 + 255) / 256, 256, 0, stream>>>(node_emb, type_emb, node_type, xb0, N);

  int aggBlocks = (3 * N + 3) / 4;  // one wave per (node, rel), 4 waves/block
  dim3 g1((N + 127) / 128, 4);
  dim3 g3((N + 127) / 128, 2);

  // layer 1: x1 = relu(rgcn(x0, w_in))
  k_aggregate<<<aggBlocks, 256, 0, stream>>>(xb0, agg, rowp, col_src, N, E);
  k_transpose<<<dim3(32, 8), 256, 0, stream>>>(w_loop_in, w_rel_in, Bt, 512, 2048);
  k_gemm_rgcn<<<g1, 256, 0, stream>>>(xb0, agg, Bt, xb1, N, 512, 2048, 1);

  // layer 2: h = rgcn(x1, w_res)  -> xb0 (x0 dead)
  k_aggregate<<<aggBlocks, 256, 0, stream>>>(xb1, agg, rowp, col_src, N, E);
  k_transpose<<<dim3(32, 8), 256, 0, stream>>>(w_loop_res, w_rel_res, Bt, 512, 2048);
  k_gemm_rgcn<<<g1, 256, 0, stream>>>(xb1, agg, Bt, xb0, N, 512, 2048, 0);

  // x2 = x1 + relu(LN(h))  -> in place over h (xb0)
  k_ln_res<<<(N + 3) / 4, 256, 0, stream>>>(xb0, xb1, ln_g, ln_b, xb0, N);

  // layer 3: z = rgcn(x2, w_out) -> z (= xb1 slot)
  k_aggregate<<<aggBlocks, 256, 0, stream>>>(xb0, agg, rowp, col_src, N, E);
  k_transpose<<<dim3(32, 4), 256, 0, stream>>>(w_loop_out, w_rel_out, Bt, 256, 2048);
  k_gemm_rgcn<<<g3, 256, 0, stream>>>(xb0, agg, Bt, z, N, 256, 2048, 0);

  // link predictor: h1 = BN(relu(feats @ W1 + b1)) -> h1 (= agg slot)
  k_transpose<<<dim3(12, 4), 256, 0, stream>>>(lp_w1, lp_w1 + 512 * 256, Bt, 256, 768);
  dim3 gl((P + 127) / 128, 2);
  k_gemm_link<<<gl, 256, 0, stream>>>(z, pairs, Bt, lp_b1, bn_g, bn_b, bn_mean, bn_var, h1, P, 768);

  // final score
  k_score<<<(P + 3) / 4, 256, 0, stream>>>(h1, lp_w2, lp_b2, pairs, degrees, alpha, beta, out, P);
}

// Round 4
// 1262.823 us; speedup vs baseline: 1.0245x; 1.0245x over previous
//
#include <hip/hip_runtime.h>

typedef __attribute__((ext_vector_type(8))) _Float16 half8;
typedef __attribute__((ext_vector_type(4))) _Float16 half4;
typedef __attribute__((ext_vector_type(4))) float f32x4;

static __device__ __forceinline__ void gload16(const void* g, void* l) {
  __builtin_amdgcn_global_load_lds((const __attribute__((address_space(1))) void*)g,
                                   (__attribute__((address_space(3))) void*)l, 16, 0, 0);
}

// ---------------- encode: x0 = fp16(node_emb + type_emb[type]) ----------------
__global__ void k_encode(const float* __restrict__ emb, const float* __restrict__ temb,
                         const int* __restrict__ tids, _Float16* __restrict__ x, int n) {
  int i = blockIdx.x * 256 + threadIdx.x;  // one thread per 8 columns
  if (i >= n * 64) return;
  int node = i >> 6, c = (i & 63) << 3;
  const float* e = emb + (size_t)node * 512 + c;
  const float* t = temb + (size_t)tids[node] * 512 + c;
  float4 a0 = *(const float4*)e, a1 = *(const float4*)(e + 4);
  float4 b0 = *(const float4*)t, b1 = *(const float4*)(t + 4);
  half8 o;
  o[0] = (_Float16)(a0.x + b0.x); o[1] = (_Float16)(a0.y + b0.y);
  o[2] = (_Float16)(a0.z + b0.z); o[3] = (_Float16)(a0.w + b0.w);
  o[4] = (_Float16)(a1.x + b1.x); o[5] = (_Float16)(a1.y + b1.y);
  o[6] = (_Float16)(a1.z + b1.z); o[7] = (_Float16)(a1.w + b1.w);
  *(half8*)(x + (size_t)node * 512 + c) = o;
}

// ---------------- CSR build ----------------
__global__ void k_zero(int* __restrict__ p, int n) {
  int i = blockIdx.x * 256 + threadIdx.x;
  if (i < n) p[i] = 0;
}

__global__ void k_hist(const int* __restrict__ d0, const int* __restrict__ d1,
                       const int* __restrict__ d2, int* __restrict__ counts, int E, int Np1) {
  int e = blockIdx.x * 256 + threadIdx.x;
  if (e >= E) return;
  int r = blockIdx.y;
  const int* d = (r == 0) ? d0 : ((r == 1) ? d1 : d2);
  atomicAdd(&counts[r * Np1 + d[e] + 1], 1);
}

// one block (1024 thr) per relation; inclusive scan of counts -> row_ptr
__global__ void k_scan(const int* __restrict__ counts, int* __restrict__ rowp, int n) {
  __shared__ int wsum[16];
  int r = blockIdx.x;
  const int* c = counts + (size_t)r * n;
  int* o = rowp + (size_t)r * n;
  int lane = threadIdx.x & 63, w = threadIdx.x >> 6;
  int off = 0;
  for (int base = 0; base < n; base += 1024) {
    int i = base + threadIdx.x;
    int v = (i < n) ? c[i] : 0;
    int sc = v;
    #pragma unroll
    for (int d = 1; d < 64; d <<= 1) {
      int t = __shfl_up(sc, (unsigned)d);
      if (lane >= d) sc += t;
    }
    if (lane == 63) wsum[w] = sc;
    __syncthreads();
    int wo = 0, tot = 0;
    #pragma unroll
    for (int ww = 0; ww < 16; ++ww) {
      int s = wsum[ww];
      if (ww < w) wo += s;
      tot += s;
    }
    if (i < n) o[i] = sc + wo + off;
    off += tot;
    __syncthreads();
  }
}

__global__ void k_copy(const int* __restrict__ a, int* __restrict__ b, int n) {
  int i = blockIdx.x * 256 + threadIdx.x;
  if (i < n) b[i] = a[i];
}

__global__ void k_fill(const int* __restrict__ s0, const int* __restrict__ s1, const int* __restrict__ s2,
                       const int* __restrict__ d0, const int* __restrict__ d1, const int* __restrict__ d2,
                       int* __restrict__ cursor, int* __restrict__ col_src, int E, int Np1) {
  int e = blockIdx.x * 256 + threadIdx.x;
  if (e >= E) return;
  int r = blockIdx.y;
  const int* dp = (r == 0) ? d0 : ((r == 1) ? d1 : d2);
  const int* sp = (r == 0) ? s0 : ((r == 1) ? s1 : s2);
  int pos = atomicAdd(&cursor[r * Np1 + dp[e]], 1);
  if (pos >= 0 && pos < E) col_src[(size_t)r * E + pos] = sp[e];
}

// ---------------- aggregate: one wave per (node, relation); fp16 in/out, fp32 accum ----------------
__global__ void k_aggregate(const _Float16* __restrict__ x, _Float16* __restrict__ agg,
                            const int* __restrict__ rowp, const int* __restrict__ col_src,
                            int N, int E) {
  int wid = (blockIdx.x * 256 + threadIdx.x) >> 6;
  int lane = threadIdx.x & 63;
  if (wid >= 3 * N) return;
  int r = wid / N;
  int n = wid - r * N;
  int beg = rowp[r * (N + 1) + n], end = rowp[r * (N + 1) + n + 1];
  const int* cs = col_src + (size_t)r * E;
  float acc[8] = {0, 0, 0, 0, 0, 0, 0, 0};
  for (int e = beg; e < end; ++e) {
    int s = cs[e];
    half8 v = *(const half8*)(x + (size_t)s * 512 + lane * 8);
    #pragma unroll
    for (int j = 0; j < 8; ++j) acc[j] += (float)v[j];
  }
  half8 o;
  #pragma unroll
  for (int j = 0; j < 8; ++j) o[j] = (_Float16)acc[j];
  *(half8*)(agg + (size_t)n * 1536 + r * 512 + lane * 8) = o;
}

// ---------------- weight transpose+cast: Bt[n][k] fp16 from Bl[k<512][n], Br[k-512][n] ----------------
__global__ void k_transpose(const float* __restrict__ Bl, const float* __restrict__ Br,
                            _Float16* __restrict__ Bt, int No, int K) {
  __shared__ float tile[64][65];
  int k0 = blockIdx.x * 64, n0 = blockIdx.y * 64;
  int nl = threadIdx.x & 63, kb = threadIdx.x >> 6;
  #pragma unroll
  for (int i = 0; i < 16; ++i) {
    int kl = kb + i * 4;
    int krow = k0 + kl;
    float v = (krow < 512) ? Bl[(size_t)krow * No + n0 + nl]
                           : Br[(size_t)(krow - 512) * No + n0 + nl];
    tile[kl][nl] = v;
  }
  __syncthreads();
  int kl = threadIdx.x & 63, nb = threadIdx.x >> 6;
  #pragma unroll
  for (int i = 0; i < 16; ++i) {
    int n2 = nb + i * 4;
    Bt[(size_t)(n0 + n2) * K + k0 + kl] = (_Float16)tile[kl][n2];
  }
}

// ---------------- RGCN GEMM (m97 structure): C = [Ain | Aagg] @ Bt^T ----------------
// LDS: unpadded [128][32] fp16 per operand; staged via global_load_lds width=16.
// grid: (Ncols/128, ceil(M/128)) -- column blocks adjacent in dispatch for A-stripe L3 reuse.
__global__ __launch_bounds__(256) void k_gemm_rgcn(
    const _Float16* __restrict__ Ain, const _Float16* __restrict__ Aagg,
    const _Float16* __restrict__ Bt, _Float16* __restrict__ C,
    int M, int Ncols, int K, int relu) {
  __shared__ __align__(16) _Float16 As[128 * 32];
  __shared__ __align__(16) _Float16 Bs[128 * 32];
  int tid = threadIdx.x;
  int bn0 = blockIdx.x * 128, bm0 = blockIdx.y * 128;
  int lane = tid & 63, wv = tid >> 6;
  int wm = wv & 1, wn = wv >> 1;
  int l16 = lane & 15, quad = lane >> 4;

  // staging geometry: wave wv covers rows [wv*16, wv*16+16) and [64+wv*16, ...)
  int rl = wv * 16 + (lane >> 2);   // row-local in 64-row chunk
  int kq = (lane & 3) * 8;          // k sub-offset in halfs (16B granule)
  int ra0 = bm0 + rl;       if (ra0 >= M) ra0 = M - 1;
  int ra1 = bm0 + 64 + rl;  if (ra1 >= M) ra1 = M - 1;
  int rb0 = bn0 + rl, rb1 = bn0 + 64 + rl;

  const _Float16* pa0 = Ain + (size_t)ra0 * 512 + kq;
  const _Float16* pa1 = Ain + (size_t)ra1 * 512 + kq;
  const _Float16* pb0 = Bt + (size_t)rb0 * K + kq;
  const _Float16* pb1 = Bt + (size_t)rb1 * K + kq;
  _Float16* la0 = &As[(wv * 16) * 32];
  _Float16* la1 = &As[(64 + wv * 16) * 32];
  _Float16* lb0 = &Bs[(wv * 16) * 32];
  _Float16* lb1 = &Bs[(64 + wv * 16) * 32];

  f32x4 acc[4][4];
  #pragma unroll
  for (int i = 0; i < 4; ++i)
    #pragma unroll
    for (int j = 0; j < 4; ++j) acc[i][j] = (f32x4){0.f, 0.f, 0.f, 0.f};

  for (int k0 = 0; k0 < K; k0 += 32) {
    if (k0 == 512) {  // switch A source: self-features -> aggregated features
      pa0 = Aagg + (size_t)ra0 * 1536 + kq;
      pa1 = Aagg + (size_t)ra1 * 1536 + kq;
    }
    __syncthreads();
    gload16(pa0, la0);
    gload16(pa1, la1);
    gload16(pb0, lb0);
    gload16(pb1, lb1);
    __syncthreads();
    half8 af[4], bf[4];
    #pragma unroll
    for (int i = 0; i < 4; ++i)
      af[i] = *(const half8*)&As[(wm * 64 + i * 16 + l16) * 32 + quad * 8];
    #pragma unroll
    for (int j = 0; j < 4; ++j)
      bf[j] = *(const half8*)&Bs[(wn * 64 + j * 16 + l16) * 32 + quad * 8];
    #pragma unroll
    for (int i = 0; i < 4; ++i)
      #pragma unroll
      for (int j = 0; j < 4; ++j)
        acc[i][j] = __builtin_amdgcn_mfma_f32_16x16x32_f16(af[i], bf[j], acc[i][j], 0, 0, 0);
    pa0 += 32; pa1 += 32; pb0 += 32; pb1 += 32;
  }

  #pragma unroll
  for (int i = 0; i < 4; ++i)
    #pragma unroll
    for (int j = 0; j < 4; ++j)
      #pragma unroll
      for (int rg = 0; rg < 4; ++rg) {
        int row = bm0 + wm * 64 + i * 16 + quad * 4 + rg;
        int col = bn0 + wn * 64 + j * 16 + l16;
        if (row < M) {
          float v = acc[i][j][rg];
          if (relu) v = fmaxf(v, 0.f);
          C[(size_t)row * Ncols + col] = (_Float16)v;
        }
      }
}

// ---------------- Link GEMM: h1 = fp16(BN(relu(feats @ W1 + b1))), feats gathered from z (fp16) ----------------
#define LSTR 40

__global__ __launch_bounds__(256) void k_gemm_link(
    const _Float16* __restrict__ z, const int* __restrict__ pairs,
    const _Float16* __restrict__ Bt,
    const float* __restrict__ b1, const float* __restrict__ bng, const float* __restrict__ bnb,
    const float* __restrict__ bnm, const float* __restrict__ bnv,
    _Float16* __restrict__ h1, int P, int K) {
  __shared__ __align__(16) _Float16 As[128 * LSTR];
  __shared__ __align__(16) _Float16 Bs[128 * LSTR];
  int tid = threadIdx.x;
  int bn0 = blockIdx.x * 128, bm0 = blockIdx.y * 128;
  int lane = tid & 63, wv = tid >> 6;
  int wm = wv & 1, wn = wv >> 1;
  int l16 = lane & 15, quad = lane >> 4;
  int srow = tid >> 1, scs = (tid & 1) * 16;
  int p = bm0 + srow; if (p >= P) p = P - 1;
  int sp = pairs[p], dp = pairs[P + p];
  const _Float16* zs = z + (size_t)sp * 256;
  const _Float16* zd = z + (size_t)dp * 256;
  int bgn = bn0 + srow;

  f32x4 acc[4][4];
  #pragma unroll
  for (int i = 0; i < 4; ++i)
    #pragma unroll
    for (int j = 0; j < 4; ++j) acc[i][j] = (f32x4){0.f, 0.f, 0.f, 0.f};

  for (int k0 = 0; k0 < K; k0 += 32) {
    __syncthreads();
    int seg = k0 >> 8;
    int kk = (k0 & 255) + scs;
    __attribute__((aligned(16))) _Float16 tmp[16];
    if (seg == 0) {
      *(uint4*)tmp = *(const uint4*)(zs + kk);
      *(uint4*)(tmp + 8) = *(const uint4*)(zs + kk + 8);
    } else if (seg == 1) {
      *(uint4*)tmp = *(const uint4*)(zd + kk);
      *(uint4*)(tmp + 8) = *(const uint4*)(zd + kk + 8);
    } else {
      half8 u0 = *(const half8*)(zs + kk), u1 = *(const half8*)(zs + kk + 8);
      half8 v0 = *(const half8*)(zd + kk), v1 = *(const half8*)(zd + kk + 8);
      #pragma unroll
      for (int j = 0; j < 8; ++j) {
        tmp[j] = (_Float16)((float)u0[j] * (float)v0[j]);
        tmp[j + 8] = (_Float16)((float)u1[j] * (float)v1[j]);
      }
    }
    *(uint4*)&As[srow * LSTR + scs] = *(const uint4*)tmp;
    *(uint4*)&As[srow * LSTR + scs + 8] = *(const uint4*)(tmp + 8);
    {
      const _Float16* src = Bt + (size_t)bgn * K + k0 + scs;
      *(uint4*)&Bs[srow * LSTR + scs] = *(const uint4*)src;
      *(uint4*)&Bs[srow * LSTR + scs + 8] = *(const uint4*)(src + 8);
    }
    __syncthreads();
    half8 af[4], bf[4];
    #pragma unroll
    for (int i = 0; i < 4; ++i)
      af[i] = *(const half8*)&As[(wm * 64 + i * 16 + l16) * LSTR + quad * 8];
    #pragma unroll
    for (int j = 0; j < 4; ++j)
      bf[j] = *(const half8*)&Bs[(wn * 64 + j * 16 + l16) * LSTR + quad * 8];
    #pragma unroll
    for (int i = 0; i < 4; ++i)
      #pragma unroll
      for (int j = 0; j < 4; ++j)
        acc[i][j] = __builtin_amdgcn_mfma_f32_16x16x32_f16(af[i], bf[j], acc[i][j], 0, 0, 0);
  }

  #pragma unroll
  for (int i = 0; i < 4; ++i)
    #pragma unroll
    for (int j = 0; j < 4; ++j) {
      int col = bn0 + wn * 64 + j * 16 + l16;
      float bb1 = b1[col], m = bnm[col], rs = rsqrtf(bnv[col] + 1e-5f);
      float gg = bng[col], bb = bnb[col];
      #pragma unroll
      for (int rg = 0; rg < 4; ++rg) {
        int row = bm0 + wm * 64 + i * 16 + quad * 4 + rg;
        if (row < P) {
          float v = fmaxf(acc[i][j][rg] + bb1, 0.f);
          v = (v - m) * rs * gg + bb;
          h1[(size_t)row * 256 + col] = (_Float16)v;
        }
      }
    }
}

// ---------------- LN + relu + residual: x2 = x1 + relu(LN(h)); fp16 in/out ----------------
__global__ void k_ln_res(const _Float16* __restrict__ h, const _Float16* __restrict__ x1,
                         const float* __restrict__ g, const float* __restrict__ b,
                         _Float16* __restrict__ out, int N) {
  int wid = (blockIdx.x * 256 + threadIdx.x) >> 6;
  int lane = threadIdx.x & 63;
  if (wid >= N) return;
  int c = lane * 8;
  half8 hv = *(const half8*)(h + (size_t)wid * 512 + c);
  float hf[8];
  float s = 0.f, sq = 0.f;
  #pragma unroll
  for (int j = 0; j < 8; ++j) {
    hf[j] = (float)hv[j];
    s += hf[j];
    sq += hf[j] * hf[j];
  }
  #pragma unroll
  for (int off = 32; off; off >>= 1) {
    s += __shfl_down(s, (unsigned)off);
    sq += __shfl_down(sq, (unsigned)off);
  }
  s = __shfl(s, 0); sq = __shfl(sq, 0);
  float mu = s * (1.f / 512.f);
  float var = sq * (1.f / 512.f) - mu * mu;
  float rs = rsqrtf(var + 1e-5f);
  float4 g0 = *(const float4*)(g + c), g1 = *(const float4*)(g + c + 4);
  float4 b0 = *(const float4*)(b + c), b1 = *(const float4*)(b + c + 4);
  float gf[8] = {g0.x, g0.y, g0.z, g0.w, g1.x, g1.y, g1.z, g1.w};
  float bf[8] = {b0.x, b0.y, b0.z, b0.w, b1.x, b1.y, b1.z, b1.w};
  half8 xv = *(const half8*)(x1 + (size_t)wid * 512 + c);
  half8 o;
  #pragma unroll
  for (int j = 0; j < 8; ++j) {
    float xw = (float)xv[j];
    o[j] = (_Float16)(xw + fmaxf((hf[j] - mu) * rs * gf[j] + bf[j], 0.f));
  }
  *(half8*)(out + (size_t)wid * 512 + c) = o;
}

// ---------------- score ----------------
__global__ void k_score(const _Float16* __restrict__ h1, const float* __restrict__ w2,
                        const float* __restrict__ b2, const int* __restrict__ pairs,
                        const int* __restrict__ degrees, const float* __restrict__ alpha,
                        const float* __restrict__ beta, float* __restrict__ out, int P) {
  int wid = (blockIdx.x * 256 + threadIdx.x) >> 6;
  int lane = threadIdx.x & 63;
  if (wid >= P) return;
  int c = lane * 4;
  half4 hv = *(const half4*)(h1 + (size_t)wid * 256 + c);
  float4 wv = *(const float4*)(w2 + c);
  float s = (float)hv[0] * wv.x + (float)hv[1] * wv.y + (float)hv[2] * wv.z + (float)hv[3] * wv.w;
  #pragma unroll
  for (int off = 32; off; off >>= 1) s += __shfl_down(s, (unsigned)off);
  if (lane == 0) {
    int sp = pairs[wid], dp = pairs[P + wid];
    float sd = (float)max(degrees[sp], 1);
    float dd = (float)max(degrees[dp], 1);
    float base = s + b2[0] - fmaxf(alpha[0], 0.f) * logf(sd) - fmaxf(beta[0], 0.f) * logf(dd);
    out[wid] = base / (sqrtf(sd) * sqrtf(dd) + 1e-8f);
  }
}

extern "C" void kernel_launch(void* const* d_in, const int* in_sizes, int n_in,
                              void* d_out, int out_size, void* d_ws, size_t ws_size,
                              hipStream_t stream) {
  const int N = 50000, E = 200000, P = 100000;
  const int Np1 = N + 1;
  const int* node_type = (const int*)d_in[0];
  const int* src0 = (const int*)d_in[1]; const int* dst0 = (const int*)d_in[2];
  const int* src1 = (const int*)d_in[3]; const int* dst1 = (const int*)d_in[4];
  const int* src2 = (const int*)d_in[5]; const int* dst2 = (const int*)d_in[6];
  const int* pairs = (const int*)d_in[7];
  const int* degrees = (const int*)d_in[8];
  const float* node_emb = (const float*)d_in[9];
  const float* type_emb = (const float*)d_in[10];
  const float* w_loop_in = (const float*)d_in[11];
  const float* w_rel_in = (const float*)d_in[12];
  const float* w_loop_res = (const float*)d_in[13];
  const float* w_rel_res = (const float*)d_in[14];
  const float* ln_g = (const float*)d_in[15];
  const float* ln_b = (const float*)d_in[16];
  const float* w_loop_out = (const float*)d_in[17];
  const float* w_rel_out = (const float*)d_in[18];
  const float* lp_w1 = (const float*)d_in[19];
  const float* lp_b1 = (const float*)d_in[20];
  const float* bn_g = (const float*)d_in[21];
  const float* bn_b = (const float*)d_in[22];
  const float* bn_mean = (const float*)d_in[23];
  const float* bn_var = (const float*)d_in[24];
  const float* lp_w2 = (const float*)d_in[25];
  const float* lp_b2 = (const float*)d_in[26];
  const float* alpha = (const float*)d_in[27];
  const float* beta = (const float*)d_in[28];
  float* out = (float*)d_out;

  char* ws = (char*)d_ws;
  size_t off = 0;
  auto alloc = [&](size_t bytes) {
    void* p = ws + off;
    off = (off + bytes + 255) & ~(size_t)255;
    return p;
  };
  _Float16* xb0 = (_Float16*)alloc((size_t)N * 512 * 2);   // 51.2 MB
  _Float16* xb1 = (_Float16*)alloc((size_t)N * 512 * 2);   // 51.2 MB
  _Float16* agg = (_Float16*)alloc((size_t)N * 1536 * 2);  // 153.6 MB
  _Float16* Bt = (_Float16*)alloc((size_t)512 * 2048 * 2); // 2 MB
  int* counts = (int*)alloc((size_t)3 * Np1 * 4);
  int* rowp = (int*)alloc((size_t)3 * Np1 * 4);
  int* cursor = (int*)alloc((size_t)3 * Np1 * 4);
  int* col_src = (int*)alloc((size_t)3 * E * 4);
  if (off > ws_size) return;  // workspace too small -> fail visibly, not crash

  // aliases (lifetimes disjoint)
  _Float16* z = xb1;   // x1 dead after ln_res
  _Float16* h1 = agg;  // agg dead after layer-3 gemm

  // CSR build (dst arrays shared by all 3 layers)
  k_zero<<<(3 * Np1 + 255) / 256, 256, 0, stream>>>(counts, 3 * Np1);
  dim3 gE((E + 255) / 256, 3);
  k_hist<<<gE, 256, 0, stream>>>(dst0, dst1, dst2, counts, E, Np1);
  k_scan<<<3, 1024, 0, stream>>>(counts, rowp, Np1);
  k_copy<<<(3 * Np1 + 255) / 256, 256, 0, stream>>>(rowp, cursor, 3 * Np1);
  k_fill<<<gE, 256, 0, stream>>>(src0, src1, src2, dst0, dst1, dst2, cursor, col_src, E, Np1);

  // encode
  k_encode<<<(N * 64 + 255) / 256, 256, 0, stream>>>(node_emb, type_emb, node_type, xb0, N);

  int aggBlocks = (3 * N + 3) / 4;  // one wave per (node, rel), 4 waves/block
  dim3 g1(4, (N + 127) / 128);      // (col-blocks, row-blocks): col-adjacent dispatch
  dim3 g3(2, (N + 127) / 128);

  // layer 1: x1 = relu(rgcn(x0, w_in))
  k_aggregate<<<aggBlocks, 256, 0, stream>>>(xb0, agg, rowp, col_src, N, E);
  k_transpose<<<dim3(32, 8), 256, 0, stream>>>(w_loop_in, w_rel_in, Bt, 512, 2048);
  k_gemm_rgcn<<<g1, 256, 0, stream>>>(xb0, agg, Bt, xb1, N, 512, 2048, 1);

  // layer 2: h = rgcn(x1, w_res)  -> xb0 (x0 dead)
  k_aggregate<<<aggBlocks, 256, 0, stream>>>(xb1, agg, rowp, col_src, N, E);
  k_transpose<<<dim3(32, 8), 256, 0, stream>>>(w_loop_res, w_rel_res, Bt, 512, 2048);
  k_gemm_rgcn<<<g1, 256, 0, stream>>>(xb1, agg, Bt, xb0, N, 512, 2048, 0);

  // x2 = x1 + relu(LN(h))  -> in place over h (xb0)
  k_ln_res<<<(N + 3) / 4, 256, 0, stream>>>(xb0, xb1, ln_g, ln_b, xb0, N);

  // layer 3: z = rgcn(x2, w_out) -> z (= xb1 slot)
  k_aggregate<<<aggBlocks, 256, 0, stream>>>(xb0, agg, rowp, col_src, N, E);
  k_transpose<<<dim3(32, 4), 256, 0, stream>>>(w_loop_out, w_rel_out, Bt, 256, 2048);
  k_gemm_rgcn<<<g3, 256, 0, stream>>>(xb0, agg, Bt, z, N, 256, 2048, 0);

  // link predictor: h1 = BN(relu(feats @ W1 + b1)) -> h1 (= agg slot)
  k_transpose<<<dim3(12, 4), 256, 0, stream>>>(lp_w1, lp_w1 + 512 * 256, Bt, 256, 768);
  dim3 gl(2, (P + 127) / 128);
  k_gemm_link<<<gl, 256, 0, stream>>>(z, pairs, Bt, lp_b1, bn_g, bn_b, bn_mean, bn_var, h1, P, 768);

  // final score
  k_score<<<(P + 3) / 4, 256, 0, stream>>>(h1, lp_w2, lp_b2, pairs, degrees, alpha, beta, out, P);
}

// Round 5
// 1133.762 us; speedup vs baseline: 1.1411x; 1.1138x over previous
//
#include <hip/hip_runtime.h>

typedef __attribute__((ext_vector_type(8))) _Float16 half8;
typedef __attribute__((ext_vector_type(4))) _Float16 half4;
typedef __attribute__((ext_vector_type(4))) float f32x4;

static __device__ __forceinline__ void gload16(const void* g, void* l) {
  __builtin_amdgcn_global_load_lds((const __attribute__((address_space(1))) void*)g,
                                   (__attribute__((address_space(3))) void*)l, 16, 0, 0);
}

// ---------------- encode: x0 = fp16(node_emb + type_emb[type]) ----------------
__global__ void k_encode(const float* __restrict__ emb, const float* __restrict__ temb,
                         const int* __restrict__ tids, _Float16* __restrict__ x, int n) {
  int i = blockIdx.x * 256 + threadIdx.x;  // one thread per 8 columns
  if (i >= n * 64) return;
  int node = i >> 6, c = (i & 63) << 3;
  const float* e = emb + (size_t)node * 512 + c;
  const float* t = temb + (size_t)tids[node] * 512 + c;
  float4 a0 = *(const float4*)e, a1 = *(const float4*)(e + 4);
  float4 b0 = *(const float4*)t, b1 = *(const float4*)(t + 4);
  half8 o;
  o[0] = (_Float16)(a0.x + b0.x); o[1] = (_Float16)(a0.y + b0.y);
  o[2] = (_Float16)(a0.z + b0.z); o[3] = (_Float16)(a0.w + b0.w);
  o[4] = (_Float16)(a1.x + b1.x); o[5] = (_Float16)(a1.y + b1.y);
  o[6] = (_Float16)(a1.z + b1.z); o[7] = (_Float16)(a1.w + b1.w);
  *(half8*)(x + (size_t)node * 512 + c) = o;
}

// ---------------- CSR build ----------------
__global__ void k_zero(int* __restrict__ p, int n) {
  int i = blockIdx.x * 256 + threadIdx.x;
  if (i < n) p[i] = 0;
}

__global__ void k_hist(const int* __restrict__ d0, const int* __restrict__ d1,
                       const int* __restrict__ d2, int* __restrict__ counts, int E, int Np1) {
  int e = blockIdx.x * 256 + threadIdx.x;
  if (e >= E) return;
  int r = blockIdx.y;
  const int* d = (r == 0) ? d0 : ((r == 1) ? d1 : d2);
  atomicAdd(&counts[r * Np1 + d[e] + 1], 1);
}

// one block (1024 thr) per relation; inclusive scan of counts -> row_ptr
__global__ void k_scan(const int* __restrict__ counts, int* __restrict__ rowp, int n) {
  __shared__ int wsum[16];
  int r = blockIdx.x;
  const int* c = counts + (size_t)r * n;
  int* o = rowp + (size_t)r * n;
  int lane = threadIdx.x & 63, w = threadIdx.x >> 6;
  int off = 0;
  for (int base = 0; base < n; base += 1024) {
    int i = base + threadIdx.x;
    int v = (i < n) ? c[i] : 0;
    int sc = v;
    #pragma unroll
    for (int d = 1; d < 64; d <<= 1) {
      int t = __shfl_up(sc, (unsigned)d);
      if (lane >= d) sc += t;
    }
    if (lane == 63) wsum[w] = sc;
    __syncthreads();
    int wo = 0, tot = 0;
    #pragma unroll
    for (int ww = 0; ww < 16; ++ww) {
      int s = wsum[ww];
      if (ww < w) wo += s;
      tot += s;
    }
    if (i < n) o[i] = sc + wo + off;
    off += tot;
    __syncthreads();
  }
}

__global__ void k_copy(const int* __restrict__ a, int* __restrict__ b, int n) {
  int i = blockIdx.x * 256 + threadIdx.x;
  if (i < n) b[i] = a[i];
}

__global__ void k_fill(const int* __restrict__ s0, const int* __restrict__ s1, const int* __restrict__ s2,
                       const int* __restrict__ d0, const int* __restrict__ d1, const int* __restrict__ d2,
                       int* __restrict__ cursor, int* __restrict__ col_src, int E, int Np1) {
  int e = blockIdx.x * 256 + threadIdx.x;
  if (e >= E) return;
  int r = blockIdx.y;
  const int* dp = (r == 0) ? d0 : ((r == 1) ? d1 : d2);
  const int* sp = (r == 0) ? s0 : ((r == 1) ? s1 : s2);
  int pos = atomicAdd(&cursor[r * Np1 + dp[e]], 1);
  if (pos >= 0 && pos < E) col_src[(size_t)r * E + pos] = sp[e];
}

// ---------------- aggregate: one wave per (node, relation); fp16 in/out, fp32 accum ----------------
__global__ void k_aggregate(const _Float16* __restrict__ x, _Float16* __restrict__ agg,
                            const int* __restrict__ rowp, const int* __restrict__ col_src,
                            int N, int E) {
  int wid = (blockIdx.x * 256 + threadIdx.x) >> 6;
  int lane = threadIdx.x & 63;
  if (wid >= 3 * N) return;
  int r = wid / N;
  int n = wid - r * N;
  int beg = rowp[r * (N + 1) + n], end = rowp[r * (N + 1) + n + 1];
  const int* cs = col_src + (size_t)r * E;
  float acc[8] = {0, 0, 0, 0, 0, 0, 0, 0};
  for (int e = beg; e < end; ++e) {
    int s = cs[e];
    half8 v = *(const half8*)(x + (size_t)s * 512 + lane * 8);
    #pragma unroll
    for (int j = 0; j < 8; ++j) acc[j] += (float)v[j];
  }
  half8 o;
  #pragma unroll
  for (int j = 0; j < 8; ++j) o[j] = (_Float16)acc[j];
  *(half8*)(agg + (size_t)n * 1536 + r * 512 + lane * 8) = o;
}

// ---------------- weight transpose+cast: Bt[n][k] fp16 from Bl[k<512][n], Br[k-512][n] ----------------
__global__ void k_transpose(const float* __restrict__ Bl, const float* __restrict__ Br,
                            _Float16* __restrict__ Bt, int No, int K) {
  __shared__ float tile[64][65];
  int k0 = blockIdx.x * 64, n0 = blockIdx.y * 64;
  int nl = threadIdx.x & 63, kb = threadIdx.x >> 6;
  #pragma unroll
  for (int i = 0; i < 16; ++i) {
    int kl = kb + i * 4;
    int krow = k0 + kl;
    float v = (krow < 512) ? Bl[(size_t)krow * No + n0 + nl]
                           : Br[(size_t)(krow - 512) * No + n0 + nl];
    tile[kl][nl] = v;
  }
  __syncthreads();
  int kl = threadIdx.x & 63, nb = threadIdx.x >> 6;
  #pragma unroll
  for (int i = 0; i < 16; ++i) {
    int n2 = nb + i * 4;
    Bt[(size_t)(n0 + n2) * K + k0 + kl] = (_Float16)tile[kl][n2];
  }
}

// ---------------- RGCN GEMM (BK=64, XCD-grouped): C = [Ain | Aagg] @ Bt^T ----------------
// 1-D grid; lin -> (stripe s, col c) such that all T col-blocks of stripe s have
// lin%8 == s%8 -> same XCD -> shared per-XCD L2 serves the A k-tile once.
// LDS [128][64] halfs per operand; k-granules XOR-swizzled at staging (tile-local)
// so 128-B row stride doesn't alias banks at ds_read_b128 time.
__global__ __launch_bounds__(256) void k_gemm_rgcn(
    const _Float16* __restrict__ Ain, const _Float16* __restrict__ Aagg,
    const _Float16* __restrict__ Bt, _Float16* __restrict__ C,
    int M, int Ncols, int K, int relu, int S, int T) {
  __shared__ __align__(16) _Float16 As[128 * 64];
  __shared__ __align__(16) _Float16 Bs[128 * 64];
  int lin = blockIdx.x;
  int grp = lin / (8 * T);
  int rmd = lin - grp * 8 * T;
  int c = rmd >> 3, x = rmd & 7;
  int s = grp * 8 + x;
  if (s >= S) return;
  int bm0 = s * 128, bn0 = c * 128;

  int tid = threadIdx.x;
  int lane = tid & 63, wv = tid >> 6;
  int wm = wv & 1, wn = wv >> 1;
  int l16 = lane & 15, quad = lane >> 4;

  // staging: wave wv, round q -> 8-row chunk (wv*4+q); lane l -> row l>>3,
  // source granule (l&7)^(l>>3)  (XOR swizzle, tile-local row bits)
  int rl8 = lane >> 3;                 // 0..7
  int gs = (lane & 7) ^ rl8;           // swizzled source granule
  int rA[4], rB[4];
  const _Float16* pa[4];
  const _Float16* pb[4];
  _Float16* ldA[4];
  _Float16* ldB[4];
  #pragma unroll
  for (int q = 0; q < 4; ++q) {
    int chunk = wv * 4 + q;
    int rl = chunk * 8 + rl8;
    int ra = bm0 + rl; if (ra >= M) ra = M - 1;
    rA[q] = ra;
    rB[q] = bn0 + rl;
    pa[q] = Ain + (size_t)ra * 512 + gs * 8;
    pb[q] = Bt + (size_t)rB[q] * K + gs * 8;
    ldA[q] = &As[chunk * 8 * 64];
    ldB[q] = &Bs[chunk * 8 * 64];
  }

  f32x4 acc[4][4];
  #pragma unroll
  for (int i = 0; i < 4; ++i)
    #pragma unroll
    for (int j = 0; j < 4; ++j) acc[i][j] = (f32x4){0.f, 0.f, 0.f, 0.f};

  for (int k0 = 0; k0 < K; k0 += 64) {
    if (k0 == 512) {  // switch A source: self-features -> aggregated features
      #pragma unroll
      for (int q = 0; q < 4; ++q) pa[q] = Aagg + (size_t)rA[q] * 1536 + gs * 8;
    }
    __syncthreads();
    #pragma unroll
    for (int q = 0; q < 4; ++q) gload16(pa[q], ldA[q]);
    #pragma unroll
    for (int q = 0; q < 4; ++q) gload16(pb[q], ldB[q]);
    __syncthreads();
    #pragma unroll
    for (int sb = 0; sb < 2; ++sb) {
      half8 af[4], bf[4];
      int slot = ((sb * 4 + quad) ^ (l16 & 7)) * 8;
      #pragma unroll
      for (int i = 0; i < 4; ++i)
        af[i] = *(const half8*)&As[(wm * 64 + i * 16 + l16) * 64 + slot];
      #pragma unroll
      for (int j = 0; j < 4; ++j)
        bf[j] = *(const half8*)&Bs[(wn * 64 + j * 16 + l16) * 64 + slot];
      #pragma unroll
      for (int i = 0; i < 4; ++i)
        #pragma unroll
        for (int j = 0; j < 4; ++j)
          acc[i][j] = __builtin_amdgcn_mfma_f32_16x16x32_f16(af[i], bf[j], acc[i][j], 0, 0, 0);
    }
    #pragma unroll
    for (int q = 0; q < 4; ++q) { pa[q] += 64; pb[q] += 64; }
  }

  #pragma unroll
  for (int i = 0; i < 4; ++i)
    #pragma unroll
    for (int j = 0; j < 4; ++j)
      #pragma unroll
      for (int rg = 0; rg < 4; ++rg) {
        int row = bm0 + wm * 64 + i * 16 + quad * 4 + rg;
        int col = bn0 + wn * 64 + j * 16 + l16;
        if (row < M) {
          float v = acc[i][j][rg];
          if (relu) v = fmaxf(v, 0.f);
          C[(size_t)row * Ncols + col] = (_Float16)v;
        }
      }
}

// ---------------- Link GEMM: h1 = fp16(BN(relu(feats @ W1 + b1))), feats gathered from z (fp16) ----------------
#define LSTR 40

__global__ __launch_bounds__(256) void k_gemm_link(
    const _Float16* __restrict__ z, const int* __restrict__ pairs,
    const _Float16* __restrict__ Bt,
    const float* __restrict__ b1, const float* __restrict__ bng, const float* __restrict__ bnb,
    const float* __restrict__ bnm, const float* __restrict__ bnv,
    _Float16* __restrict__ h1, int P, int K) {
  __shared__ __align__(16) _Float16 As[128 * LSTR];
  __shared__ __align__(16) _Float16 Bs[128 * LSTR];
  int tid = threadIdx.x;
  int bn0 = blockIdx.x * 128, bm0 = blockIdx.y * 128;
  int lane = tid & 63, wv = tid >> 6;
  int wm = wv & 1, wn = wv >> 1;
  int l16 = lane & 15, quad = lane >> 4;
  int srow = tid >> 1, scs = (tid & 1) * 16;
  int p = bm0 + srow; if (p >= P) p = P - 1;
  int sp = pairs[p], dp = pairs[P + p];
  const _Float16* zs = z + (size_t)sp * 256;
  const _Float16* zd = z + (size_t)dp * 256;
  int bgn = bn0 + srow;

  f32x4 acc[4][4];
  #pragma unroll
  for (int i = 0; i < 4; ++i)
    #pragma unroll
    for (int j = 0; j < 4; ++j) acc[i][j] = (f32x4){0.f, 0.f, 0.f, 0.f};

  for (int k0 = 0; k0 < K; k0 += 32) {
    __syncthreads();
    int seg = k0 >> 8;
    int kk = (k0 & 255) + scs;
    __attribute__((aligned(16))) _Float16 tmp[16];
    if (seg == 0) {
      *(uint4*)tmp = *(const uint4*)(zs + kk);
      *(uint4*)(tmp + 8) = *(const uint4*)(zs + kk + 8);
    } else if (seg == 1) {
      *(uint4*)tmp = *(const uint4*)(zd + kk);
      *(uint4*)(tmp + 8) = *(const uint4*)(zd + kk + 8);
    } else {
      half8 u0 = *(const half8*)(zs + kk), u1 = *(const half8*)(zs + kk + 8);
      half8 v0 = *(const half8*)(zd + kk), v1 = *(const half8*)(zd + kk + 8);
      #pragma unroll
      for (int j = 0; j < 8; ++j) {
        tmp[j] = (_Float16)((float)u0[j] * (float)v0[j]);
        tmp[j + 8] = (_Float16)((float)u1[j] * (float)v1[j]);
      }
    }
    *(uint4*)&As[srow * LSTR + scs] = *(const uint4*)tmp;
    *(uint4*)&As[srow * LSTR + scs + 8] = *(const uint4*)(tmp + 8);
    {
      const _Float16* src = Bt + (size_t)bgn * K + k0 + scs;
      *(uint4*)&Bs[srow * LSTR + scs] = *(const uint4*)src;
      *(uint4*)&Bs[srow * LSTR + scs + 8] = *(const uint4*)(src + 8);
    }
    __syncthreads();
    half8 af[4], bf[4];
    #pragma unroll
    for (int i = 0; i < 4; ++i)
      af[i] = *(const half8*)&As[(wm * 64 + i * 16 + l16) * LSTR + quad * 8];
    #pragma unroll
    for (int j = 0; j < 4; ++j)
      bf[j] = *(const half8*)&Bs[(wn * 64 + j * 16 + l16) * LSTR + quad * 8];
    #pragma unroll
    for (int i = 0; i < 4; ++i)
      #pragma unroll
      for (int j = 0; j < 4; ++j)
        acc[i][j] = __builtin_amdgcn_mfma_f32_16x16x32_f16(af[i], bf[j], acc[i][j], 0, 0, 0);
  }

  #pragma unroll
  for (int i = 0; i < 4; ++i)
    #pragma unroll
    for (int j = 0; j < 4; ++j) {
      int col = bn0 + wn * 64 + j * 16 + l16;
      float bb1 = b1[col], m = bnm[col], rs = rsqrtf(bnv[col] + 1e-5f);
      float gg = bng[col], bb = bnb[col];
      #pragma unroll
      for (int rg = 0; rg < 4; ++rg) {
        int row = bm0 + wm * 64 + i * 16 + quad * 4 + rg;
        if (row < P) {
          float v = fmaxf(acc[i][j][rg] + bb1, 0.f);
          v = (v - m) * rs * gg + bb;
          h1[(size_t)row * 256 + col] = (_Float16)v;
        }
      }
    }
}

// ---------------- LN + relu + residual: x2 = x1 + relu(LN(h)); fp16 in/out ----------------
__global__ void k_ln_res(const _Float16* __restrict__ h, const _Float16* __restrict__ x1,
                         const float* __restrict__ g, const float* __restrict__ b,
                         _Float16* __restrict__ out, int N) {
  int wid = (blockIdx.x * 256 + threadIdx.x) >> 6;
  int lane = threadIdx.x & 63;
  if (wid >= N) return;
  int c = lane * 8;
  half8 hv = *(const half8*)(h + (size_t)wid * 512 + c);
  float hf[8];
  float s = 0.f, sq = 0.f;
  #pragma unroll
  for (int j = 0; j < 8; ++j) {
    hf[j] = (float)hv[j];
    s += hf[j];
    sq += hf[j] * hf[j];
  }
  #pragma unroll
  for (int off = 32; off; off >>= 1) {
    s += __shfl_down(s, (unsigned)off);
    sq += __shfl_down(sq, (unsigned)off);
  }
  s = __shfl(s, 0); sq = __shfl(sq, 0);
  float mu = s * (1.f / 512.f);
  float var = sq * (1.f / 512.f) - mu * mu;
  float rs = rsqrtf(var + 1e-5f);
  float4 g0 = *(const float4*)(g + c), g1 = *(const float4*)(g + c + 4);
  float4 b0 = *(const float4*)(b + c), b1 = *(const float4*)(b + c + 4);
  float gf[8] = {g0.x, g0.y, g0.z, g0.w, g1.x, g1.y, g1.z, g1.w};
  float bf[8] = {b0.x, b0.y, b0.z, b0.w, b1.x, b1.y, b1.z, b1.w};
  half8 xv = *(const half8*)(x1 + (size_t)wid * 512 + c);
  half8 o;
  #pragma unroll
  for (int j = 0; j < 8; ++j) {
    float xw = (float)xv[j];
    o[j] = (_Float16)(xw + fmaxf((hf[j] - mu) * rs * gf[j] + bf[j], 0.f));
  }
  *(half8*)(out + (size_t)wid * 512 + c) = o;
}

// ---------------- score ----------------
__global__ void k_score(const _Float16* __restrict__ h1, const float* __restrict__ w2,
                        const float* __restrict__ b2, const int* __restrict__ pairs,
                        const int* __restrict__ degrees, const float* __restrict__ alpha,
                        const float* __restrict__ beta, float* __restrict__ out, int P) {
  int wid = (blockIdx.x * 256 + threadIdx.x) >> 6;
  int lane = threadIdx.x & 63;
  if (wid >= P) return;
  int c = lane * 4;
  half4 hv = *(const half4*)(h1 + (size_t)wid * 256 + c);
  float4 wv = *(const float4*)(w2 + c);
  float s = (float)hv[0] * wv.x + (float)hv[1] * wv.y + (float)hv[2] * wv.z + (float)hv[3] * wv.w;
  #pragma unroll
  for (int off = 32; off; off >>= 1) s += __shfl_down(s, (unsigned)off);
  if (lane == 0) {
    int sp = pairs[wid], dp = pairs[P + wid];
    float sd = (float)max(degrees[sp], 1);
    float dd = (float)max(degrees[dp], 1);
    float base = s + b2[0] - fmaxf(alpha[0], 0.f) * logf(sd) - fmaxf(beta[0], 0.f) * logf(dd);
    out[wid] = base / (sqrtf(sd) * sqrtf(dd) + 1e-8f);
  }
}

extern "C" void kernel_launch(void* const* d_in, const int* in_sizes, int n_in,
                              void* d_out, int out_size, void* d_ws, size_t ws_size,
                              hipStream_t stream) {
  const int N = 50000, E = 200000, P = 100000;
  const int Np1 = N + 1;
  const int* node_type = (const int*)d_in[0];
  const int* src0 = (const int*)d_in[1]; const int* dst0 = (const int*)d_in[2];
  const int* src1 = (const int*)d_in[3]; const int* dst1 = (const int*)d_in[4];
  const int* src2 = (const int*)d_in[5]; const int* dst2 = (const int*)d_in[6];
  const int* pairs = (const int*)d_in[7];
  const int* degrees = (const int*)d_in[8];
  const float* node_emb = (const float*)d_in[9];
  const float* type_emb = (const float*)d_in[10];
  const float* w_loop_in = (const float*)d_in[11];
  const float* w_rel_in = (const float*)d_in[12];
  const float* w_loop_res = (const float*)d_in[13];
  const float* w_rel_res = (const float*)d_in[14];
  const float* ln_g = (const float*)d_in[15];
  const float* ln_b = (const float*)d_in[16];
  const float* w_loop_out = (const float*)d_in[17];
  const float* w_rel_out = (const float*)d_in[18];
  const float* lp_w1 = (const float*)d_in[19];
  const float* lp_b1 = (const float*)d_in[20];
  const float* bn_g = (const float*)d_in[21];
  const float* bn_b = (const float*)d_in[22];
  const float* bn_mean = (const float*)d_in[23];
  const float* bn_var = (const float*)d_in[24];
  const float* lp_w2 = (const float*)d_in[25];
  const float* lp_b2 = (const float*)d_in[26];
  const float* alpha = (const float*)d_in[27];
  const float* beta = (const float*)d_in[28];
  float* out = (float*)d_out;

  char* ws = (char*)d_ws;
  size_t off = 0;
  auto alloc = [&](size_t bytes) {
    void* p = ws + off;
    off = (off + bytes + 255) & ~(size_t)255;
    return p;
  };
  _Float16* xb0 = (_Float16*)alloc((size_t)N * 512 * 2);   // 51.2 MB
  _Float16* xb1 = (_Float16*)alloc((size_t)N * 512 * 2);   // 51.2 MB
  _Float16* agg = (_Float16*)alloc((size_t)N * 1536 * 2);  // 153.6 MB
  _Float16* Bt = (_Float16*)alloc((size_t)512 * 2048 * 2); // 2 MB
  int* counts = (int*)alloc((size_t)3 * Np1 * 4);
  int* rowp = (int*)alloc((size_t)3 * Np1 * 4);
  int* cursor = (int*)alloc((size_t)3 * Np1 * 4);
  int* col_src = (int*)alloc((size_t)3 * E * 4);
  if (off > ws_size) return;  // workspace too small -> fail visibly, not crash

  // aliases (lifetimes disjoint)
  _Float16* z = xb1;   // x1 dead after ln_res
  _Float16* h1 = agg;  // agg dead after layer-3 gemm

  // CSR build (dst arrays shared by all 3 layers)
  k_zero<<<(3 * Np1 + 255) / 256, 256, 0, stream>>>(counts, 3 * Np1);
  dim3 gE((E + 255) / 256, 3);
  k_hist<<<gE, 256, 0, stream>>>(dst0, dst1, dst2, counts, E, Np1);
  k_scan<<<3, 1024, 0, stream>>>(counts, rowp, Np1);
  k_copy<<<(3 * Np1 + 255) / 256, 256, 0, stream>>>(rowp, cursor, 3 * Np1);
  k_fill<<<gE, 256, 0, stream>>>(src0, src1, src2, dst0, dst1, dst2, cursor, col_src, E, Np1);

  // encode
  k_encode<<<(N * 64 + 255) / 256, 256, 0, stream>>>(node_emb, type_emb, node_type, xb0, N);

  int aggBlocks = (3 * N + 3) / 4;   // one wave per (node, rel), 4 waves/block
  const int S = (N + 127) / 128;     // 391 row stripes
  int blocks4 = ((S + 7) / 8) * 8 * 4;  // XCD-grouped 1-D grid, T=4
  int blocks2 = ((S + 7) / 8) * 8 * 2;  // T=2

  // layer 1: x1 = relu(rgcn(x0, w_in))
  k_aggregate<<<aggBlocks, 256, 0, stream>>>(xb0, agg, rowp, col_src, N, E);
  k_transpose<<<dim3(32, 8), 256, 0, stream>>>(w_loop_in, w_rel_in, Bt, 512, 2048);
  k_gemm_rgcn<<<blocks4, 256, 0, stream>>>(xb0, agg, Bt, xb1, N, 512, 2048, 1, S, 4);

  // layer 2: h = rgcn(x1, w_res)  -> xb0 (x0 dead)
  k_aggregate<<<aggBlocks, 256, 0, stream>>>(xb1, agg, rowp, col_src, N, E);
  k_transpose<<<dim3(32, 8), 256, 0, stream>>>(w_loop_res, w_rel_res, Bt, 512, 2048);
  k_gemm_rgcn<<<blocks4, 256, 0, stream>>>(xb1, agg, Bt, xb0, N, 512, 2048, 0, S, 4);

  // x2 = x1 + relu(LN(h))  -> in place over h (xb0)
  k_ln_res<<<(N + 3) / 4, 256, 0, stream>>>(xb0, xb1, ln_g, ln_b, xb0, N);

  // layer 3: z = rgcn(x2, w_out) -> z (= xb1 slot)
  k_aggregate<<<aggBlocks, 256, 0, stream>>>(xb0, agg, rowp, col_src, N, E);
  k_transpose<<<dim3(32, 4), 256, 0, stream>>>(w_loop_out, w_rel_out, Bt, 256, 2048);
  k_gemm_rgcn<<<blocks2, 256, 0, stream>>>(xb0, agg, Bt, z, N, 256, 2048, 0, S, 2);

  // link predictor: h1 = BN(relu(feats @ W1 + b1)) -> h1 (= agg slot)
  k_transpose<<<dim3(12, 4), 256, 0, stream>>>(lp_w1, lp_w1 + 512 * 256, Bt, 256, 768);
  dim3 gl(2, (P + 127) / 128);
  k_gemm_link<<<gl, 256, 0, stream>>>(z, pairs, Bt, lp_b1, bn_g, bn_b, bn_mean, bn_var, h1, P, 768);

  // final score
  k_score<<<(P + 3) / 4, 256, 0, stream>>>(h1, lp_w2, lp_b2, pairs, degrees, alpha, beta, out, P);
}

// Round 6
// 1058.068 us; speedup vs baseline: 1.2227x; 1.0715x over previous
//
#include <hip/hip_runtime.h>

typedef __attribute__((ext_vector_type(8))) _Float16 half8;
typedef __attribute__((ext_vector_type(4))) _Float16 half4;
typedef __attribute__((ext_vector_type(4))) float f32x4;

static __device__ __forceinline__ void gload16(const void* g, void* l) {
  __builtin_amdgcn_global_load_lds((const __attribute__((address_space(1))) void*)g,
                                   (__attribute__((address_space(3))) void*)l, 16, 0, 0);
}

// ---------------- encode: x0 = fp16(node_emb + type_emb[type]) ----------------
__global__ void k_encode(const float* __restrict__ emb, const float* __restrict__ temb,
                         const int* __restrict__ tids, _Float16* __restrict__ x, int n) {
  int i = blockIdx.x * 256 + threadIdx.x;  // one thread per 8 columns
  if (i >= n * 64) return;
  int node = i >> 6, c = (i & 63) << 3;
  const float* e = emb + (size_t)node * 512 + c;
  const float* t = temb + (size_t)tids[node] * 512 + c;
  float4 a0 = *(const float4*)e, a1 = *(const float4*)(e + 4);
  float4 b0 = *(const float4*)t, b1 = *(const float4*)(t + 4);
  half8 o;
  o[0] = (_Float16)(a0.x + b0.x); o[1] = (_Float16)(a0.y + b0.y);
  o[2] = (_Float16)(a0.z + b0.z); o[3] = (_Float16)(a0.w + b0.w);
  o[4] = (_Float16)(a1.x + b1.x); o[5] = (_Float16)(a1.y + b1.y);
  o[6] = (_Float16)(a1.z + b1.z); o[7] = (_Float16)(a1.w + b1.w);
  *(half8*)(x + (size_t)node * 512 + c) = o;
}

// ---------------- CSR build ----------------
__global__ void k_zero(int* __restrict__ p, int n) {
  int i = blockIdx.x * 256 + threadIdx.x;
  if (i < n) p[i] = 0;
}

__global__ void k_hist(const int* __restrict__ d0, const int* __restrict__ d1,
                       const int* __restrict__ d2, int* __restrict__ counts, int E, int Np1) {
  int e = blockIdx.x * 256 + threadIdx.x;
  if (e >= E) return;
  int r = blockIdx.y;
  const int* d = (r == 0) ? d0 : ((r == 1) ? d1 : d2);
  atomicAdd(&counts[r * Np1 + d[e] + 1], 1);
}

// one block (1024 thr) per relation; inclusive scan of counts -> row_ptr
__global__ void k_scan(const int* __restrict__ counts, int* __restrict__ rowp, int n) {
  __shared__ int wsum[16];
  int r = blockIdx.x;
  const int* c = counts + (size_t)r * n;
  int* o = rowp + (size_t)r * n;
  int lane = threadIdx.x & 63, w = threadIdx.x >> 6;
  int off = 0;
  for (int base = 0; base < n; base += 1024) {
    int i = base + threadIdx.x;
    int v = (i < n) ? c[i] : 0;
    int sc = v;
    #pragma unroll
    for (int d = 1; d < 64; d <<= 1) {
      int t = __shfl_up(sc, (unsigned)d);
      if (lane >= d) sc += t;
    }
    if (lane == 63) wsum[w] = sc;
    __syncthreads();
    int wo = 0, tot = 0;
    #pragma unroll
    for (int ww = 0; ww < 16; ++ww) {
      int s = wsum[ww];
      if (ww < w) wo += s;
      tot += s;
    }
    if (i < n) o[i] = sc + wo + off;
    off += tot;
    __syncthreads();
  }
}

__global__ void k_copy(const int* __restrict__ a, int* __restrict__ b, int n) {
  int i = blockIdx.x * 256 + threadIdx.x;
  if (i < n) b[i] = a[i];
}

__global__ void k_fill(const int* __restrict__ s0, const int* __restrict__ s1, const int* __restrict__ s2,
                       const int* __restrict__ d0, const int* __restrict__ d1, const int* __restrict__ d2,
                       int* __restrict__ cursor, int* __restrict__ col_src, int E, int Np1) {
  int e = blockIdx.x * 256 + threadIdx.x;
  if (e >= E) return;
  int r = blockIdx.y;
  const int* dp = (r == 0) ? d0 : ((r == 1) ? d1 : d2);
  const int* sp = (r == 0) ? s0 : ((r == 1) ? s1 : s2);
  int pos = atomicAdd(&cursor[r * Np1 + dp[e]], 1);
  if (pos >= 0 && pos < E) col_src[(size_t)r * E + pos] = sp[e];
}

// ---------------- aggregate: one wave per node, all 3 relations; fp16 in/out, fp32 accum ----------------
__global__ void k_aggregate(const _Float16* __restrict__ x, _Float16* __restrict__ agg,
                            const int* __restrict__ rowp, const int* __restrict__ col_src,
                            int N, int E) {
  int wid = (blockIdx.x * 256 + threadIdx.x) >> 6;
  int lane = threadIdx.x & 63;
  if (wid >= N) return;
  int Np1 = N + 1;
  #pragma unroll
  for (int r = 0; r < 3; ++r) {
    int beg = rowp[r * Np1 + wid], end = rowp[r * Np1 + wid + 1];
    const int* cs = col_src + (size_t)r * E;
    float acc[8] = {0, 0, 0, 0, 0, 0, 0, 0};
    int sn = (beg < end) ? cs[beg] : 0;
    for (int e = beg; e < end; ++e) {
      int sc = sn;
      if (e + 1 < end) sn = cs[e + 1];  // prefetch next index while row loads
      half8 v = *(const half8*)(x + (size_t)sc * 512 + lane * 8);
      #pragma unroll
      for (int j = 0; j < 8; ++j) acc[j] += (float)v[j];
    }
    half8 o;
    #pragma unroll
    for (int j = 0; j < 8; ++j) o[j] = (_Float16)acc[j];
    *(half8*)(agg + (size_t)wid * 1536 + r * 512 + lane * 8) = o;
  }
}

// ---------------- all-weights transpose+cast in ONE launch ----------------
// z selects matrix: 0:w_in(512,2048) 1:w_res(512,2048) 2:w_out(256,2048) 3:lp_w1(256,768)
__global__ void k_transpose_all(const float* __restrict__ wli, const float* __restrict__ wri,
                                const float* __restrict__ wlr, const float* __restrict__ wrr,
                                const float* __restrict__ wlo, const float* __restrict__ wro,
                                const float* __restrict__ lpw1,
                                _Float16* __restrict__ Bti, _Float16* __restrict__ Btr,
                                _Float16* __restrict__ Bto, _Float16* __restrict__ Btl) {
  __shared__ float tile[64][65];
  int zi = blockIdx.z;
  const float* Bl; const float* Br; _Float16* Bt; int No, K;
  if (zi == 0)      { Bl = wli;  Br = wri;            Bt = Bti; No = 512; K = 2048; }
  else if (zi == 1) { Bl = wlr;  Br = wrr;            Bt = Btr; No = 512; K = 2048; }
  else if (zi == 2) { Bl = wlo;  Br = wro;            Bt = Bto; No = 256; K = 2048; }
  else              { Bl = lpw1; Br = lpw1 + 512*256; Bt = Btl; No = 256; K = 768;  }
  int k0 = blockIdx.x * 64, n0 = blockIdx.y * 64;
  if (k0 >= K || n0 >= No) return;
  int nl = threadIdx.x & 63, kb = threadIdx.x >> 6;
  #pragma unroll
  for (int i = 0; i < 16; ++i) {
    int kl = kb + i * 4;
    int krow = k0 + kl;
    float v = (krow < 512) ? Bl[(size_t)krow * No + n0 + nl]
                           : Br[(size_t)(krow - 512) * No + n0 + nl];
    tile[kl][nl] = v;
  }
  __syncthreads();
  int kl = threadIdx.x & 63, nb = threadIdx.x >> 6;
  #pragma unroll
  for (int i = 0; i < 16; ++i) {
    int n2 = nb + i * 4;
    Bt[(size_t)(n0 + n2) * K + k0 + kl] = (_Float16)tile[kl][n2];
  }
}

// ---------------- RGCN GEMM (256x128 tile, BK=64, XCD-grouped): C = [Ain | Aagg] @ Bt^T ----------------
// 8 waves/block. 1-D grid; all T col-blocks of a stripe share lin%8 -> same XCD L2.
// LDS k-granules XOR-swizzled at staging so 128-B row stride doesn't alias banks.
__global__ __launch_bounds__(512) void k_gemm_rgcn(
    const _Float16* __restrict__ Ain, const _Float16* __restrict__ Aagg,
    const _Float16* __restrict__ Bt, _Float16* __restrict__ C,
    int M, int Ncols, int K, int relu, int S, int T) {
  __shared__ __align__(16) _Float16 As[256 * 64];
  __shared__ __align__(16) _Float16 Bs[128 * 64];
  int lin = blockIdx.x;
  int grp = lin / (8 * T);
  int rmd = lin - grp * 8 * T;
  int c = rmd >> 3, x = rmd & 7;
  int s = grp * 8 + x;
  if (s >= S) return;
  int bm0 = s * 256, bn0 = c * 128;

  int tid = threadIdx.x;
  int lane = tid & 63, wv = tid >> 6;       // wv 0..7
  int wm = wv & 3, wn = wv >> 2;            // 4x2 wave grid
  int l16 = lane & 15, quad = lane >> 4;

  int rl8 = lane >> 3;                 // row-in-chunk 0..7
  int gs = (lane & 7) ^ rl8;           // swizzled source granule

  int rA[4];
  const _Float16* pa[4];
  const _Float16* pb[2];
  _Float16* ldA[4];
  _Float16* ldB[2];
  #pragma unroll
  for (int q = 0; q < 4; ++q) {
    int chunk = wv * 4 + q;            // 0..31 -> 256 A rows
    int rl = chunk * 8 + rl8;
    int ra = bm0 + rl; if (ra >= M) ra = M - 1;
    rA[q] = ra;
    pa[q] = Ain + (size_t)ra * 512 + gs * 8;
    ldA[q] = &As[chunk * 8 * 64];
  }
  #pragma unroll
  for (int q = 0; q < 2; ++q) {
    int chunk = wv * 2 + q;            // 0..15 -> 128 B rows
    int rl = chunk * 8 + rl8;
    pb[q] = Bt + (size_t)(bn0 + rl) * K + gs * 8;
    ldB[q] = &Bs[chunk * 8 * 64];
  }

  f32x4 acc[4][4];
  #pragma unroll
  for (int i = 0; i < 4; ++i)
    #pragma unroll
    for (int j = 0; j < 4; ++j) acc[i][j] = (f32x4){0.f, 0.f, 0.f, 0.f};

  for (int k0 = 0; k0 < K; k0 += 64) {
    if (k0 == 512) {  // switch A source: self-features -> aggregated features
      #pragma unroll
      for (int q = 0; q < 4; ++q) pa[q] = Aagg + (size_t)rA[q] * 1536 + gs * 8;
    }
    __syncthreads();
    #pragma unroll
    for (int q = 0; q < 4; ++q) gload16(pa[q], ldA[q]);
    #pragma unroll
    for (int q = 0; q < 2; ++q) gload16(pb[q], ldB[q]);
    __syncthreads();
    #pragma unroll
    for (int sb = 0; sb < 2; ++sb) {
      half8 af[4], bf[4];
      int slot = ((sb * 4 + quad) ^ (l16 & 7)) * 8;
      #pragma unroll
      for (int i = 0; i < 4; ++i)
        af[i] = *(const half8*)&As[(wm * 64 + i * 16 + l16) * 64 + slot];
      #pragma unroll
      for (int j = 0; j < 4; ++j)
        bf[j] = *(const half8*)&Bs[(wn * 64 + j * 16 + l16) * 64 + slot];
      #pragma unroll
      for (int i = 0; i < 4; ++i)
        #pragma unroll
        for (int j = 0; j < 4; ++j)
          acc[i][j] = __builtin_amdgcn_mfma_f32_16x16x32_f16(af[i], bf[j], acc[i][j], 0, 0, 0);
    }
    #pragma unroll
    for (int q = 0; q < 4; ++q) pa[q] += 64;
    #pragma unroll
    for (int q = 0; q < 2; ++q) pb[q] += 64;
  }

  #pragma unroll
  for (int i = 0; i < 4; ++i)
    #pragma unroll
    for (int j = 0; j < 4; ++j)
      #pragma unroll
      for (int rg = 0; rg < 4; ++rg) {
        int row = bm0 + wm * 64 + i * 16 + quad * 4 + rg;
        int col = bn0 + wn * 64 + j * 16 + l16;
        if (row < M) {
          float v = acc[i][j][rg];
          if (relu) v = fmaxf(v, 0.f);
          C[(size_t)row * Ncols + col] = (_Float16)v;
        }
      }
}

// ---------------- Link GEMM: h1 = fp16(BN(relu(feats @ W1 + b1))), feats gathered from z (fp16) ----------------
#define LSTR 40

__global__ __launch_bounds__(256) void k_gemm_link(
    const _Float16* __restrict__ z, const int* __restrict__ pairs,
    const _Float16* __restrict__ Bt,
    const float* __restrict__ b1, const float* __restrict__ bng, const float* __restrict__ bnb,
    const float* __restrict__ bnm, const float* __restrict__ bnv,
    _Float16* __restrict__ h1, int P, int K) {
  __shared__ __align__(16) _Float16 As[128 * LSTR];
  __shared__ __align__(16) _Float16 Bs[128 * LSTR];
  int tid = threadIdx.x;
  int bn0 = blockIdx.x * 128, bm0 = blockIdx.y * 128;
  int lane = tid & 63, wv = tid >> 6;
  int wm = wv & 1, wn = wv >> 1;
  int l16 = lane & 15, quad = lane >> 4;
  int srow = tid >> 1, scs = (tid & 1) * 16;
  int p = bm0 + srow; if (p >= P) p = P - 1;
  int sp = pairs[p], dp = pairs[P + p];
  const _Float16* zs = z + (size_t)sp * 256;
  const _Float16* zd = z + (size_t)dp * 256;
  int bgn = bn0 + srow;

  f32x4 acc[4][4];
  #pragma unroll
  for (int i = 0; i < 4; ++i)
    #pragma unroll
    for (int j = 0; j < 4; ++j) acc[i][j] = (f32x4){0.f, 0.f, 0.f, 0.f};

  for (int k0 = 0; k0 < K; k0 += 32) {
    __syncthreads();
    int seg = k0 >> 8;
    int kk = (k0 & 255) + scs;
    __attribute__((aligned(16))) _Float16 tmp[16];
    if (seg == 0) {
      *(uint4*)tmp = *(const uint4*)(zs + kk);
      *(uint4*)(tmp + 8) = *(const uint4*)(zs + kk + 8);
    } else if (seg == 1) {
      *(uint4*)tmp = *(const uint4*)(zd + kk);
      *(uint4*)(tmp + 8) = *(const uint4*)(zd + kk + 8);
    } else {
      half8 u0 = *(const half8*)(zs + kk), u1 = *(const half8*)(zs + kk + 8);
      half8 v0 = *(const half8*)(zd + kk), v1 = *(const half8*)(zd + kk + 8);
      #pragma unroll
      for (int j = 0; j < 8; ++j) {
        tmp[j] = (_Float16)((float)u0[j] * (float)v0[j]);
        tmp[j + 8] = (_Float16)((float)u1[j] * (float)v1[j]);
      }
    }
    *(uint4*)&As[srow * LSTR + scs] = *(const uint4*)tmp;
    *(uint4*)&As[srow * LSTR + scs + 8] = *(const uint4*)(tmp + 8);
    {
      const _Float16* src = Bt + (size_t)bgn * K + k0 + scs;
      *(uint4*)&Bs[srow * LSTR + scs] = *(const uint4*)src;
      *(uint4*)&Bs[srow * LSTR + scs + 8] = *(const uint4*)(src + 8);
    }
    __syncthreads();
    half8 af[4], bf[4];
    #pragma unroll
    for (int i = 0; i < 4; ++i)
      af[i] = *(const half8*)&As[(wm * 64 + i * 16 + l16) * LSTR + quad * 8];
    #pragma unroll
    for (int j = 0; j < 4; ++j)
      bf[j] = *(const half8*)&Bs[(wn * 64 + j * 16 + l16) * LSTR + quad * 8];
    #pragma unroll
    for (int i = 0; i < 4; ++i)
      #pragma unroll
      for (int j = 0; j < 4; ++j)
        acc[i][j] = __builtin_amdgcn_mfma_f32_16x16x32_f16(af[i], bf[j], acc[i][j], 0, 0, 0);
  }

  #pragma unroll
  for (int i = 0; i < 4; ++i)
    #pragma unroll
    for (int j = 0; j < 4; ++j) {
      int col = bn0 + wn * 64 + j * 16 + l16;
      float bb1 = b1[col], m = bnm[col], rs = rsqrtf(bnv[col] + 1e-5f);
      float gg = bng[col], bb = bnb[col];
      #pragma unroll
      for (int rg = 0; rg < 4; ++rg) {
        int row = bm0 + wm * 64 + i * 16 + quad * 4 + rg;
        if (row < P) {
          float v = fmaxf(acc[i][j][rg] + bb1, 0.f);
          v = (v - m) * rs * gg + bb;
          h1[(size_t)row * 256 + col] = (_Float16)v;
        }
      }
    }
}

// ---------------- LN + relu + residual: x2 = x1 + relu(LN(h)); fp16 in/out ----------------
__global__ void k_ln_res(const _Float16* __restrict__ h, const _Float16* __restrict__ x1,
                         const float* __restrict__ g, const float* __restrict__ b,
                         _Float16* __restrict__ out, int N) {
  int wid = (blockIdx.x * 256 + threadIdx.x) >> 6;
  int lane = threadIdx.x & 63;
  if (wid >= N) return;
  int c = lane * 8;
  half8 hv = *(const half8*)(h + (size_t)wid * 512 + c);
  float hf[8];
  float s = 0.f, sq = 0.f;
  #pragma unroll
  for (int j = 0; j < 8; ++j) {
    hf[j] = (float)hv[j];
    s += hf[j];
    sq += hf[j] * hf[j];
  }
  #pragma unroll
  for (int off = 32; off; off >>= 1) {
    s += __shfl_down(s, (unsigned)off);
    sq += __shfl_down(sq, (unsigned)off);
  }
  s = __shfl(s, 0); sq = __shfl(sq, 0);
  float mu = s * (1.f / 512.f);
  float var = sq * (1.f / 512.f) - mu * mu;
  float rs = rsqrtf(var + 1e-5f);
  float4 g0 = *(const float4*)(g + c), g1 = *(const float4*)(g + c + 4);
  float4 b0 = *(const float4*)(b + c), b1 = *(const float4*)(b + c + 4);
  float gf[8] = {g0.x, g0.y, g0.z, g0.w, g1.x, g1.y, g1.z, g1.w};
  float bf[8] = {b0.x, b0.y, b0.z, b0.w, b1.x, b1.y, b1.z, b1.w};
  half8 xv = *(const half8*)(x1 + (size_t)wid * 512 + c);
  half8 o;
  #pragma unroll
  for (int j = 0; j < 8; ++j) {
    float xw = (float)xv[j];
    o[j] = (_Float16)(xw + fmaxf((hf[j] - mu) * rs * gf[j] + bf[j], 0.f));
  }
  *(half8*)(out + (size_t)wid * 512 + c) = o;
}

// ---------------- score ----------------
__global__ void k_score(const _Float16* __restrict__ h1, const float* __restrict__ w2,
                        const float* __restrict__ b2, const int* __restrict__ pairs,
                        const int* __restrict__ degrees, const float* __restrict__ alpha,
                        const float* __restrict__ beta, float* __restrict__ out, int P) {
  int wid = (blockIdx.x * 256 + threadIdx.x) >> 6;
  int lane = threadIdx.x & 63;
  if (wid >= P) return;
  int c = lane * 4;
  half4 hv = *(const half4*)(h1 + (size_t)wid * 256 + c);
  float4 wv = *(const float4*)(w2 + c);
  float s = (float)hv[0] * wv.x + (float)hv[1] * wv.y + (float)hv[2] * wv.z + (float)hv[3] * wv.w;
  #pragma unroll
  for (int off = 32; off; off >>= 1) s += __shfl_down(s, (unsigned)off);
  if (lane == 0) {
    int sp = pairs[wid], dp = pairs[P + wid];
    float sd = (float)max(degrees[sp], 1);
    float dd = (float)max(degrees[dp], 1);
    float base = s + b2[0] - fmaxf(alpha[0], 0.f) * logf(sd) - fmaxf(beta[0], 0.f) * logf(dd);
    out[wid] = base / (sqrtf(sd) * sqrtf(dd) + 1e-8f);
  }
}

extern "C" void kernel_launch(void* const* d_in, const int* in_sizes, int n_in,
                              void* d_out, int out_size, void* d_ws, size_t ws_size,
                              hipStream_t stream) {
  const int N = 50000, E = 200000, P = 100000;
  const int Np1 = N + 1;
  const int* node_type = (const int*)d_in[0];
  const int* src0 = (const int*)d_in[1]; const int* dst0 = (const int*)d_in[2];
  const int* src1 = (const int*)d_in[3]; const int* dst1 = (const int*)d_in[4];
  const int* src2 = (const int*)d_in[5]; const int* dst2 = (const int*)d_in[6];
  const int* pairs = (const int*)d_in[7];
  const int* degrees = (const int*)d_in[8];
  const float* node_emb = (const float*)d_in[9];
  const float* type_emb = (const float*)d_in[10];
  const float* w_loop_in = (const float*)d_in[11];
  const float* w_rel_in = (const float*)d_in[12];
  const float* w_loop_res = (const float*)d_in[13];
  const float* w_rel_res = (const float*)d_in[14];
  const float* ln_g = (const float*)d_in[15];
  const float* ln_b = (const float*)d_in[16];
  const float* w_loop_out = (const float*)d_in[17];
  const float* w_rel_out = (const float*)d_in[18];
  const float* lp_w1 = (const float*)d_in[19];
  const float* lp_b1 = (const float*)d_in[20];
  const float* bn_g = (const float*)d_in[21];
  const float* bn_b = (const float*)d_in[22];
  const float* bn_mean = (const float*)d_in[23];
  const float* bn_var = (const float*)d_in[24];
  const float* lp_w2 = (const float*)d_in[25];
  const float* lp_b2 = (const float*)d_in[26];
  const float* alpha = (const float*)d_in[27];
  const float* beta = (const float*)d_in[28];
  float* out = (float*)d_out;

  char* ws = (char*)d_ws;
  size_t off = 0;
  auto alloc = [&](size_t bytes) {
    void* p = ws + off;
    off = (off + bytes + 255) & ~(size_t)255;
    return p;
  };
  _Float16* xb0 = (_Float16*)alloc((size_t)N * 512 * 2);    // 51.2 MB
  _Float16* xb1 = (_Float16*)alloc((size_t)N * 512 * 2);    // 51.2 MB
  _Float16* agg = (_Float16*)alloc((size_t)N * 1536 * 2);   // 153.6 MB
  _Float16* Bti = (_Float16*)alloc((size_t)512 * 2048 * 2); // 2 MB
  _Float16* Btr = (_Float16*)alloc((size_t)512 * 2048 * 2); // 2 MB
  _Float16* Bto = (_Float16*)alloc((size_t)256 * 2048 * 2); // 1 MB
  _Float16* Btl = (_Float16*)alloc((size_t)256 * 768 * 2);  // 0.4 MB
  int* counts = (int*)alloc((size_t)3 * Np1 * 4);
  int* rowp = (int*)alloc((size_t)3 * Np1 * 4);
  int* cursor = (int*)alloc((size_t)3 * Np1 * 4);
  int* col_src = (int*)alloc((size_t)3 * E * 4);
  if (off > ws_size) return;  // workspace too small -> fail visibly, not crash

  // aliases (lifetimes disjoint)
  _Float16* z = xb1;   // x1 dead after ln_res
  _Float16* h1 = agg;  // agg dead after layer-3 gemm

  // all weight transposes up front (one launch)
  k_transpose_all<<<dim3(32, 8, 4), 256, 0, stream>>>(
      w_loop_in, w_rel_in, w_loop_res, w_rel_res, w_loop_out, w_rel_out, lp_w1,
      Bti, Btr, Bto, Btl);

  // CSR build (dst arrays shared by all 3 layers)
  k_zero<<<(3 * Np1 + 255) / 256, 256, 0, stream>>>(counts, 3 * Np1);
  dim3 gE((E + 255) / 256, 3);
  k_hist<<<gE, 256, 0, stream>>>(dst0, dst1, dst2, counts, E, Np1);
  k_scan<<<3, 1024, 0, stream>>>(counts, rowp, Np1);
  k_copy<<<(3 * Np1 + 255) / 256, 256, 0, stream>>>(rowp, cursor, 3 * Np1);
  k_fill<<<gE, 256, 0, stream>>>(src0, src1, src2, dst0, dst1, dst2, cursor, col_src, E, Np1);

  // encode
  k_encode<<<(N * 64 + 255) / 256, 256, 0, stream>>>(node_emb, type_emb, node_type, xb0, N);

  int aggBlocks = (N + 3) / 4;       // one wave per node (3 relations each)
  const int S = (N + 255) / 256;     // 196 row stripes of 256
  int blocks4 = ((S + 7) / 8) * 8 * 4;  // XCD-grouped 1-D grid, T=4
  int blocks2 = ((S + 7) / 8) * 8 * 2;  // T=2

  // layer 1: x1 = relu(rgcn(x0, w_in))
  k_aggregate<<<aggBlocks, 256, 0, stream>>>(xb0, agg, rowp, col_src, N, E);
  k_gemm_rgcn<<<blocks4, 512, 0, stream>>>(xb0, agg, Bti, xb1, N, 512, 2048, 1, S, 4);

  // layer 2: h = rgcn(x1, w_res)  -> xb0 (x0 dead)
  k_aggregate<<<aggBlocks, 256, 0, stream>>>(xb1, agg, rowp, col_src, N, E);
  k_gemm_rgcn<<<blocks4, 512, 0, stream>>>(xb1, agg, Btr, xb0, N, 512, 2048, 0, S, 4);

  // x2 = x1 + relu(LN(h))  -> in place over h (xb0)
  k_ln_res<<<(N + 3) / 4, 256, 0, stream>>>(xb0, xb1, ln_g, ln_b, xb0, N);

  // layer 3: z = rgcn(x2, w_out) -> z (= xb1 slot)
  k_aggregate<<<aggBlocks, 256, 0, stream>>>(xb0, agg, rowp, col_src, N, E);
  k_gemm_rgcn<<<blocks2, 512, 0, stream>>>(xb0, agg, Bto, z, N, 256, 2048, 0, S, 2);

  // link predictor: h1 = BN(relu(feats @ W1 + b1)) -> h1 (= agg slot)
  dim3 gl(2, (P + 127) / 128);
  k_gemm_link<<<gl, 256, 0, stream>>>(z, pairs, Btl, lp_b1, bn_g, bn_b, bn_mean, bn_var, h1, P, 768);

  // final score
  k_score<<<(P + 3) / 4, 256, 0, stream>>>(h1, lp_w2, lp_b2, pairs, degrees, alpha, beta, out, P);
}